// Round 1
// baseline (1102.208 us; speedup 1.0000x reference)
//
#include <hip/hip_runtime.h>
#include <hip/hip_fp16.h>

// Problem constants (fixed by reference)
#define BSZ   1024
#define INDIM 768
#define PROJ  9216     // 256*6*6
#define NCAP  512      // 32 caps * 16 spatial
#define NCLS  5

// ---------- bf16 helpers (own impl: deterministic RNE, no API surprises) ----
static __device__ __forceinline__ unsigned short f2bf(float f) {
  unsigned int x = __float_as_uint(f);
  unsigned int r = (x + 0x7fffu + ((x >> 16) & 1u)) >> 16;
  return (unsigned short)r;
}
static __device__ __forceinline__ float bf2f(unsigned int u) {
  return __uint_as_float(u << 16);
}

// =====================================================================
// Kernel 1: h = relu(x @ W1 + b1), stored bf16.  M=1024 K=768 N=9216
// BM=128 BN=64 BK=16, 256 threads, 8x4 per thread.
// =====================================================================
#define BM 128
#define BN 64
#define BK 16

__global__ __launch_bounds__(256) void gemm_relu_bf16out(
    const float* __restrict__ A, const float* __restrict__ W,
    const float* __restrict__ bias, unsigned short* __restrict__ H) {
  __shared__ float As[BK][BM];
  __shared__ float Bs[BK][BN];
  const int t  = threadIdx.x;
  const int bn = blockIdx.x * BN;
  const int bm = blockIdx.y * BM;
  const int tx = t & 15;         // n-group
  const int ty = t >> 4;         // m-group
  const int ar = t >> 1;         // 0..127
  const int ac = (t & 1) << 3;   // 0 or 8
  const int br = t >> 4;         // 0..15
  const int bc = (t & 15) << 2;  // 0..60

  float acc[8][4];
#pragma unroll
  for (int i = 0; i < 8; ++i)
#pragma unroll
    for (int j = 0; j < 4; ++j) acc[i][j] = 0.f;

  const float* Aptr = A + (size_t)(bm + ar) * INDIM + ac;
  const float* Wptr = W + (size_t)br * PROJ + bn + bc;

  for (int k0 = 0; k0 < INDIM; k0 += BK) {
    float4 a0 = *(const float4*)(Aptr + k0);
    float4 a1 = *(const float4*)(Aptr + k0 + 4);
    float4 b0 = *(const float4*)(Wptr + (size_t)k0 * PROJ);
    __syncthreads();  // previous tile fully consumed before overwrite
    As[ac + 0][ar] = a0.x; As[ac + 1][ar] = a0.y;
    As[ac + 2][ar] = a0.z; As[ac + 3][ar] = a0.w;
    As[ac + 4][ar] = a1.x; As[ac + 5][ar] = a1.y;
    As[ac + 6][ar] = a1.z; As[ac + 7][ar] = a1.w;
    *(float4*)(&Bs[br][bc]) = b0;
    __syncthreads();
#pragma unroll
    for (int k = 0; k < BK; ++k) {
      float a[8], b[4];
      *(float4*)(&a[0]) = *(const float4*)(&As[k][ty * 8]);
      *(float4*)(&a[4]) = *(const float4*)(&As[k][ty * 8 + 4]);
      *(float4*)(&b[0]) = *(const float4*)(&Bs[k][tx * 4]);
#pragma unroll
      for (int i = 0; i < 8; ++i)
#pragma unroll
        for (int j = 0; j < 4; ++j) acc[i][j] += a[i] * b[j];
    }
  }
  float4 bb = *(const float4*)(bias + bn + tx * 4);
  float bv[4] = {bb.x, bb.y, bb.z, bb.w};
#pragma unroll
  for (int i = 0; i < 8; ++i) {
    ushort4 s;
    s.x = f2bf(fmaxf(acc[i][0] + bv[0], 0.f));
    s.y = f2bf(fmaxf(acc[i][1] + bv[1], 0.f));
    s.z = f2bf(fmaxf(acc[i][2] + bv[2], 0.f));
    s.w = f2bf(fmaxf(acc[i][3] + bv[3], 0.f));
    *(ushort4*)(H + (size_t)(bm + ty * 8 + i) * PROJ + bn + tx * 4) = s;
  }
}

// =====================================================================
// Kernel 2: conv 3x3 VALID (256ch 6x6 -> 256ch 4x4) + capsule squash.
// One block per batch element, 256 threads (one per out channel).
// u[b, cap*16+p, i] = squash_i(conv[b, cap*8+i, p]), stored bf16.
// =====================================================================
__global__ __launch_bounds__(256) void conv_squash(
    const unsigned short* __restrict__ H, const float* __restrict__ convW,
    const float* __restrict__ convB, unsigned short* __restrict__ U) {
  __shared__ __align__(16) unsigned short hbuf[PROJ];  // 18 KB
  const int b = blockIdx.x;
  const int t = threadIdx.x;
  {
    const uint2* src = (const uint2*)(H + (size_t)b * PROJ);
    uint2* dst = (uint2*)hbuf;
#pragma unroll
    for (int i = 0; i < 9; ++i) dst[t + i * 256] = src[t + i * 256];
  }
  __syncthreads();

  const int oc = t;
  float acc[16];
  const float cb = convB[oc];
#pragma unroll
  for (int p = 0; p < 16; ++p) acc[p] = cb;

  const float* wbase = convW + (size_t)oc * 2304;
  for (int ic = 0; ic < 256; ++ic) {
    float w[9];
#pragma unroll
    for (int j = 0; j < 9; ++j) w[j] = wbase[ic * 9 + j];
    float ph[36];
    {
      const uint2* pr = (const uint2*)(&hbuf[ic * 36]);  // 72B, 8B-aligned
#pragma unroll
      for (int j = 0; j < 9; ++j) {
        uint2 q = pr[j];
        ph[j * 4 + 0] = bf2f(q.x & 0xffffu);
        ph[j * 4 + 1] = bf2f(q.x >> 16);
        ph[j * 4 + 2] = bf2f(q.y & 0xffffu);
        ph[j * 4 + 3] = bf2f(q.y >> 16);
      }
    }
#pragma unroll
    for (int ki = 0; ki < 3; ++ki)
#pragma unroll
      for (int kj = 0; kj < 3; ++kj) {
        const float wv = w[ki * 3 + kj];
#pragma unroll
        for (int pi = 0; pi < 4; ++pi)
#pragma unroll
          for (int pj = 0; pj < 4; ++pj)
            acc[pi * 4 + pj] += wv * ph[(pi + ki) * 6 + (pj + kj)];
      }
  }

  // squash over the 8 channels of each capsule (8 consecutive lanes)
  const int cap = t >> 3, ii = t & 7;
  unsigned short* ub = U + (size_t)b * (NCAP * 8) + (cap << 7) + ii;
#pragma unroll
  for (int p = 0; p < 16; ++p) {
    float sq = acc[p] * acc[p];
    sq += __shfl_xor(sq, 1);
    sq += __shfl_xor(sq, 2);
    sq += __shfl_xor(sq, 4);
    const float scale = sq / (1.f + sq) / sqrtf(sq + 1e-8f);
    ub[p * 8] = f2bf(acc[p] * scale);
  }
}

// =====================================================================
// Kernel 3: fused u_hat + dynamic routing. One block per batch element,
// 256 threads; each thread owns 2 input capsules. u_hat in registers (f16).
// out = [class_probs (1024*5) | v (1024*5*16)]  (f32)
// =====================================================================
__global__ __launch_bounds__(256, 1) void routing(
    const unsigned short* __restrict__ U, const float* __restrict__ Wr,
    float* __restrict__ out) {
  __shared__ float red[4][80];
  __shared__ float vsh[80];
  const int b = blockIdx.x;
  const int t = threadIdx.x;

  // load u for caps n = 2t, 2t+1
  float ul[2][8];
  {
    const unsigned short* ub = U + (size_t)b * (NCAP * 8) + t * 16;
    uint4 q0 = *(const uint4*)(ub);
    uint4 q1 = *(const uint4*)(ub + 8);
    ul[0][0] = bf2f(q0.x & 0xffffu); ul[0][1] = bf2f(q0.x >> 16);
    ul[0][2] = bf2f(q0.y & 0xffffu); ul[0][3] = bf2f(q0.y >> 16);
    ul[0][4] = bf2f(q0.z & 0xffffu); ul[0][5] = bf2f(q0.z >> 16);
    ul[0][6] = bf2f(q0.w & 0xffffu); ul[0][7] = bf2f(q0.w >> 16);
    ul[1][0] = bf2f(q1.x & 0xffffu); ul[1][1] = bf2f(q1.x >> 16);
    ul[1][2] = bf2f(q1.y & 0xffffu); ul[1][3] = bf2f(q1.y >> 16);
    ul[1][4] = bf2f(q1.z & 0xffffu); ul[1][5] = bf2f(q1.z >> 16);
    ul[1][6] = bf2f(q1.w & 0xffffu); ul[1][7] = bf2f(q1.w >> 16);
  }

  // u_hat[n, o, d] = sum_i Wr[n,o,d,i] * u[n,i]; kept as half2 (d pairs)
  __half2 uh[2][5][8];
#pragma unroll
  for (int c = 0; c < 2; ++c) {
    const float* wp = Wr + (size_t)(2 * t + c) * 640;
#pragma unroll
    for (int o = 0; o < 5; ++o)
#pragma unroll
      for (int dp = 0; dp < 8; ++dp) {
        const float* w0 = wp + o * 128 + dp * 16;
        float s0 = 0.f, s1 = 0.f;
#pragma unroll
        for (int i = 0; i < 8; ++i) {
          s0 += w0[i] * ul[c][i];
          s1 += w0[8 + i] * ul[c][i];
        }
        uh[c][o][dp] = __floats2half2_rn(s0, s1);
      }
  }

  float blog[2][5];
#pragma unroll
  for (int c = 0; c < 2; ++c)
#pragma unroll
    for (int o = 0; o < 5; ++o) blog[c][o] = 0.f;

  for (int it = 0; it < 3; ++it) {
    float spart[80];
#pragma unroll
    for (int j = 0; j < 80; ++j) spart[j] = 0.f;
#pragma unroll
    for (int c = 0; c < 2; ++c) {
      float m = blog[c][0];
#pragma unroll
      for (int o = 1; o < 5; ++o) m = fmaxf(m, blog[c][o]);
      float e[5], es = 0.f;
#pragma unroll
      for (int o = 0; o < 5; ++o) { e[o] = __expf(blog[c][o] - m); es += e[o]; }
      const float inv = 1.f / es;
#pragma unroll
      for (int o = 0; o < 5; ++o) {
        const float cc = e[o] * inv;
#pragma unroll
        for (int dp = 0; dp < 8; ++dp) {
          const float2 f = __half22float2(uh[c][o][dp]);
          spart[o * 16 + dp * 2 + 0] += cc * f.x;
          spart[o * 16 + dp * 2 + 1] += cc * f.y;
        }
      }
    }
    // wave-level sum then cross-wave combine
#pragma unroll
    for (int off = 32; off > 0; off >>= 1)
#pragma unroll
      for (int j = 0; j < 80; ++j) spart[j] += __shfl_xor(spart[j], off);
    if ((t & 63) == 0) {
      const int w = t >> 6;
#pragma unroll
      for (int j = 0; j < 80; ++j) red[w][j] = spart[j];
    }
    __syncthreads();
    if (t < 80) {
      const float s = red[0][t] + red[1][t] + red[2][t] + red[3][t];
      float sq = s * s;
      sq += __shfl_xor(sq, 1);
      sq += __shfl_xor(sq, 2);
      sq += __shfl_xor(sq, 4);
      sq += __shfl_xor(sq, 8);
      const float scale = sq / (1.f + sq) / sqrtf(sq + 1e-8f);
      const float v = s * scale;
      vsh[t] = v;
      if (it == 2) {
        out[5 * BSZ + (size_t)b * 80 + t] = v;
        float vv = v * v;
        vv += __shfl_xor(vv, 1);
        vv += __shfl_xor(vv, 2);
        vv += __shfl_xor(vv, 4);
        vv += __shfl_xor(vv, 8);
        if ((t & 15) == 0) out[(size_t)b * 5 + (t >> 4)] = sqrtf(vv);
      }
    }
    __syncthreads();
    if (it < 2) {
#pragma unroll
      for (int c = 0; c < 2; ++c)
#pragma unroll
        for (int o = 0; o < 5; ++o) {
          float ag = 0.f;
#pragma unroll
          for (int dp = 0; dp < 8; ++dp) {
            const float2 f = __half22float2(uh[c][o][dp]);
            ag += f.x * vsh[o * 16 + dp * 2] + f.y * vsh[o * 16 + dp * 2 + 1];
          }
          blog[c][o] += ag;
        }
    }
  }
}

// =====================================================================
extern "C" void kernel_launch(void* const* d_in, const int* in_sizes, int n_in,
                              void* d_out, int out_size, void* d_ws, size_t ws_size,
                              hipStream_t stream) {
  const float* x     = (const float*)d_in[0];
  const float* W1    = (const float*)d_in[1];
  const float* b1    = (const float*)d_in[2];
  const float* convW = (const float*)d_in[3];
  const float* convB = (const float*)d_in[4];
  const float* Wr    = (const float*)d_in[5];
  float* out = (float*)d_out;

  // ws layout: h bf16 [1024*9216] (18.9 MB), u bf16 [1024*4096] (8.4 MB)
  unsigned short* h = (unsigned short*)d_ws;
  unsigned short* u = h + (size_t)BSZ * PROJ;

  dim3 gg(PROJ / BN, BSZ / BM);  // (144, 8)
  gemm_relu_bf16out<<<gg, 256, 0, stream>>>(x, W1, b1, h);
  conv_squash<<<BSZ, 256, 0, stream>>>(h, convW, convB, u);
  routing<<<BSZ, 256, 0, stream>>>(u, Wr, out);
}

// Round 2
// 516.464 us; speedup vs baseline: 2.1341x; 2.1341x over previous
//
#include <hip/hip_runtime.h>
#include <hip/hip_fp16.h>

#define BSZ   1024
#define INDIM 768
#define PROJ  9216     // 256*6*6
#define NCAP  512
#define NCLS  5
#define KPAD  3072     // 256 ic * 12 (9 taps + 3 zero pad)

typedef __bf16 bf16x8 __attribute__((ext_vector_type(8)));
typedef float  f32x4  __attribute__((ext_vector_type(4)));

static __device__ __forceinline__ unsigned short f2bf(float f) {
  unsigned int x = __float_as_uint(f);
  return (unsigned short)((x + 0x7fffu + ((x >> 16) & 1u)) >> 16);
}
static __device__ __forceinline__ float bf2f(unsigned int u) {
  return __uint_as_float(u << 16);
}

// global -> LDS direct (16B per lane). CK-style addrspace cast via uintptr.
static __device__ __forceinline__ void gload16(const void* g, void* l) {
  auto gp = reinterpret_cast<const unsigned int __attribute__((address_space(1)))*>(
      (unsigned long long)g);
  auto lp = reinterpret_cast<unsigned int __attribute__((address_space(3)))*>(
      (unsigned long long)l);
  __builtin_amdgcn_global_load_lds(gp, lp, 16, 0, 0);
}

// =====================================================================
// Unified bf16 MFMA GEMM: C[M][N] = A[M][K] * Bt[N][K]^T + bias[N]
// 128x128 tile, BK=32, 256 threads (4 waves, each 64x64 = 4x4 16x16 tiles).
// 2-phase double-buffered global_load_lds staging; 4-slot XOR swizzle on
// the k-chunk (applied to BOTH stage-source and frag-read; involution).
// =====================================================================
template <int RELU, int OBF16>
__global__ __launch_bounds__(256) void mfma_gemm(
    const unsigned short* __restrict__ A,   // [M][K] bf16
    const unsigned short* __restrict__ Bt,  // [N][K] bf16
    const float* __restrict__ bias,         // [N]
    void* __restrict__ Cout,                // [M][N] f32 or bf16
    int M, int N, int K) {
  __shared__ __align__(16) unsigned short smem[16384];  // 2 bufs * (A 4096 + B 4096)
  const int t    = threadIdx.x;
  const int bn   = blockIdx.x * 128;
  const int bm   = blockIdx.y * 128;
  const int lane = t & 63;
  const int wid  = t >> 6;
  const int wm   = (wid >> 1) * 64;
  const int wn   = (wid & 1) * 64;
  const int l15  = lane & 15;
  const int kb   = lane >> 4;  // k-block 0..3

  // staging: chunk c -> (row = c>>2, kc = c&3); this thread stages c=t, c=t+256
  const int r0 = t >> 2,         kc = t & 3;
  const int r1 = (t + 256) >> 2;
  const int gk0 = ((kc ^ (r0 & 3)) << 3);  // swizzled source k within 32
  const int gk1 = ((kc ^ (r1 & 3)) << 3);

  const unsigned short* Ar0 = A  + (size_t)(bm + r0) * K + gk0;
  const unsigned short* Ar1 = A  + (size_t)(bm + r1) * K + gk1;
  const unsigned short* Br0 = Bt + (size_t)(bn + r0) * K + gk0;
  const unsigned short* Br1 = Bt + (size_t)(bn + r1) * K + gk1;

  // fragment LDS offsets (ushort units): row stride 32, chunk = 8 ushorts
  int aoff[4], boff[4];
#pragma unroll
  for (int i = 0; i < 4; ++i) {
    const int ra = wm + i * 16 + l15;
    aoff[i] = ra * 32 + ((kb ^ (ra & 3)) << 3);
    const int rb = wn + i * 16 + l15;
    boff[i] = 4096 + rb * 32 + ((kb ^ (rb & 3)) << 3);
  }

  f32x4 acc[4][4];
#pragma unroll
  for (int i = 0; i < 4; ++i)
#pragma unroll
    for (int j = 0; j < 4; ++j)
#pragma unroll
      for (int q = 0; q < 4; ++q) acc[i][j][q] = 0.f;

  const int nk = K >> 5;
  // prologue: stage K-step 0 into buf 0
  gload16(Ar0, &smem[t * 8]);
  gload16(Ar1, &smem[(t + 256) * 8]);
  gload16(Br0, &smem[4096 + t * 8]);
  gload16(Br1, &smem[4096 + (t + 256) * 8]);
  __syncthreads();

  int buf = 0;
  for (int ks = 0; ks < nk; ++ks) {
    if (ks + 1 < nk) {
      const int k = (ks + 1) << 5;
      const int o = (buf ^ 1) * 8192;
      gload16(Ar0 + k, &smem[o + t * 8]);
      gload16(Ar1 + k, &smem[o + (t + 256) * 8]);
      gload16(Br0 + k, &smem[o + 4096 + t * 8]);
      gload16(Br1 + k, &smem[o + 4096 + (t + 256) * 8]);
    }
    const unsigned short* base = &smem[buf * 8192];
    bf16x8 af[4], bfr[4];
#pragma unroll
    for (int i = 0; i < 4; ++i) {
      af[i]  = *(const bf16x8*)(base + aoff[i]);
      bfr[i] = *(const bf16x8*)(base + boff[i]);
    }
#pragma unroll
    for (int i = 0; i < 4; ++i)
#pragma unroll
      for (int j = 0; j < 4; ++j)
        acc[i][j] = __builtin_amdgcn_mfma_f32_16x16x32_bf16(af[i], bfr[j], acc[i][j], 0, 0, 0);
    __syncthreads();
    buf ^= 1;
  }

  // epilogue: C/D layout col = lane&15, row = (lane>>4)*4 + q  [m89-verified]
#pragma unroll
  for (int j = 0; j < 4; ++j) {
    const int col = bn + wn + j * 16 + l15;
    const float bv = bias[col];
#pragma unroll
    for (int i = 0; i < 4; ++i) {
#pragma unroll
      for (int q = 0; q < 4; ++q) {
        const int row = bm + wm + i * 16 + kb * 4 + q;
        float v = acc[i][j][q] + bv;
        if (RELU) v = fmaxf(v, 0.f);
        if (OBF16) ((unsigned short*)Cout)[(size_t)row * N + col] = f2bf(v);
        else       ((float*)Cout)[(size_t)row * N + col] = v;
      }
    }
  }
}

// =====================================================================
// Transforms
// =====================================================================
__global__ __launch_bounds__(256) void convert_x(const float* __restrict__ in,
                                                 unsigned short* __restrict__ out) {
  const int i = blockIdx.x * 256 + threadIdx.x;  // 196608 float4 groups
  float4 v = ((const float4*)in)[i];
  ushort4 o;
  o.x = f2bf(v.x); o.y = f2bf(v.y); o.z = f2bf(v.z); o.w = f2bf(v.w);
  ((ushort4*)out)[i] = o;
}

// W1 [768][9216] f32 -> W1t [9216][768] bf16 (32x32 LDS-tiled transpose)
__global__ __launch_bounds__(256) void transpose_w1(const float* __restrict__ W,
                                                    unsigned short* __restrict__ Wt) {
  __shared__ float tile[32][33];
  const int n0 = blockIdx.x * 32, k0 = blockIdx.y * 32;
  const int r = threadIdx.x >> 3, c = (threadIdx.x & 7) * 4;
  float4 v = *(const float4*)(W + (size_t)(k0 + r) * PROJ + n0 + c);
  tile[r][c] = v.x; tile[r][c + 1] = v.y; tile[r][c + 2] = v.z; tile[r][c + 3] = v.w;
  __syncthreads();
  ushort4 o;
  o.x = f2bf(tile[c + 0][r]); o.y = f2bf(tile[c + 1][r]);
  o.z = f2bf(tile[c + 2][r]); o.w = f2bf(tile[c + 3][r]);
  *(ushort4*)(Wt + (size_t)(n0 + r) * INDIM + k0 + c) = o;
}

// convW [oc][ic][9] f32 -> Wb [oc][ic*12 + r] bf16, r=9..11 zero
__global__ __launch_bounds__(256) void convw_prep(const float* __restrict__ W,
                                                  unsigned short* __restrict__ Wb) {
  const int id = blockIdx.x * 256 + threadIdx.x;  // oc*256 + ic, 65536 total
  const float* s = W + (size_t)id * 9;
  unsigned int v[9];
#pragma unroll
  for (int j = 0; j < 9; ++j) v[j] = f2bf(s[j]);
  uint2* d = (uint2*)(Wb + (size_t)id * 12);
  d[0] = make_uint2(v[0] | (v[1] << 16), v[2] | (v[3] << 16));
  d[1] = make_uint2(v[4] | (v[5] << 16), v[6] | (v[7] << 16));
  d[2] = make_uint2(v[8], 0u);
}

// im2col: h[b][ic][36] bf16 -> Bm[(b-b0)*16+p][ic*12+r] bf16 (pad r=9..11)
// one block per b; thread = ic; LDS bounce for coalesced row writes.
__global__ __launch_bounds__(256) void im2col(const unsigned short* __restrict__ H,
                                              unsigned short* __restrict__ Bm, int b0) {
  __shared__ unsigned int rowbuf[1536];  // one 6144B output row
  const int b = b0 + blockIdx.x;
  const int t = threadIdx.x;  // = ic
  unsigned int hu[18];
  const uint2* src = (const uint2*)(H + (size_t)b * PROJ + t * 36);
#pragma unroll
  for (int j = 0; j < 9; ++j) { uint2 q = src[j]; hu[2 * j] = q.x; hu[2 * j + 1] = q.y; }
#pragma unroll
  for (int p = 0; p < 16; ++p) {
    const int pi = p >> 2, pj = p & 3;
    unsigned int v[9];
#pragma unroll
    for (int r = 0; r < 9; ++r) {
      const int j = (pi + r / 3) * 6 + pj + (r % 3);
      v[r] = (hu[j >> 1] >> ((j & 1) * 16)) & 0xffffu;
    }
    if (p) __syncthreads();
    rowbuf[t * 6 + 0] = v[0] | (v[1] << 16);
    rowbuf[t * 6 + 1] = v[2] | (v[3] << 16);
    rowbuf[t * 6 + 2] = v[4] | (v[5] << 16);
    rowbuf[t * 6 + 3] = v[6] | (v[7] << 16);
    rowbuf[t * 6 + 4] = v[8];
    rowbuf[t * 6 + 5] = 0u;
    __syncthreads();
    uint2* dst = (uint2*)(Bm + ((size_t)blockIdx.x * 16 + p) * KPAD);
    const uint2* rb = (const uint2*)rowbuf;
#pragma unroll
    for (int j = 0; j < 3; ++j) dst[t + j * 256] = rb[t + j * 256];
  }
}

// squash: cv[(b*16+p)][oc=cap*8+i] f32 (bias already added) -> U[b][cap][p][i] bf16
__global__ __launch_bounds__(256) void squash_u(const float* __restrict__ cv,
                                                unsigned short* __restrict__ U) {
  const int b = blockIdx.x;
  const int t = threadIdx.x;
#pragma unroll
  for (int h = 0; h < 2; ++h) {
    const int id = t + h * 256;
    const int cap = id & 31, p = id >> 5;
    const float* s = cv + ((size_t)b * 16 + p) * 256 + cap * 8;
    float4 a = *(const float4*)s;
    float4 c = *(const float4*)(s + 4);
    float sq = a.x * a.x + a.y * a.y + a.z * a.z + a.w * a.w +
               c.x * c.x + c.y * c.y + c.z * c.z + c.w * c.w;
    const float scale = sq / (1.f + sq) / sqrtf(sq + 1e-8f);
    unsigned short* d = U + (size_t)b * 4096 + cap * 128 + p * 8;
    ushort4 o0, o1;
    o0.x = f2bf(a.x * scale); o0.y = f2bf(a.y * scale);
    o0.z = f2bf(a.z * scale); o0.w = f2bf(a.w * scale);
    o1.x = f2bf(c.x * scale); o1.y = f2bf(c.y * scale);
    o1.z = f2bf(c.z * scale); o1.w = f2bf(c.w * scale);
    *(ushort4*)d = o0; *(ushort4*)(d + 4) = o1;
  }
}

// =====================================================================
// Kernel: fused u_hat + dynamic routing (unchanged from R1, passing)
// =====================================================================
__global__ __launch_bounds__(256, 1) void routing(
    const unsigned short* __restrict__ U, const float* __restrict__ Wr,
    float* __restrict__ out) {
  __shared__ float red[4][80];
  __shared__ float vsh[80];
  const int b = blockIdx.x;
  const int t = threadIdx.x;

  float ul[2][8];
  {
    const unsigned short* ub = U + (size_t)b * (NCAP * 8) + t * 16;
    uint4 q0 = *(const uint4*)(ub);
    uint4 q1 = *(const uint4*)(ub + 8);
    ul[0][0] = bf2f(q0.x & 0xffffu); ul[0][1] = bf2f(q0.x >> 16);
    ul[0][2] = bf2f(q0.y & 0xffffu); ul[0][3] = bf2f(q0.y >> 16);
    ul[0][4] = bf2f(q0.z & 0xffffu); ul[0][5] = bf2f(q0.z >> 16);
    ul[0][6] = bf2f(q0.w & 0xffffu); ul[0][7] = bf2f(q0.w >> 16);
    ul[1][0] = bf2f(q1.x & 0xffffu); ul[1][1] = bf2f(q1.x >> 16);
    ul[1][2] = bf2f(q1.y & 0xffffu); ul[1][3] = bf2f(q1.y >> 16);
    ul[1][4] = bf2f(q1.z & 0xffffu); ul[1][5] = bf2f(q1.z >> 16);
    ul[1][6] = bf2f(q1.w & 0xffffu); ul[1][7] = bf2f(q1.w >> 16);
  }

  __half2 uh[2][5][8];
#pragma unroll
  for (int c = 0; c < 2; ++c) {
    const float* wp = Wr + (size_t)(2 * t + c) * 640;
#pragma unroll
    for (int o = 0; o < 5; ++o)
#pragma unroll
      for (int dp = 0; dp < 8; ++dp) {
        const float* w0 = wp + o * 128 + dp * 16;
        float s0 = 0.f, s1 = 0.f;
#pragma unroll
        for (int i = 0; i < 8; ++i) {
          s0 += w0[i] * ul[c][i];
          s1 += w0[8 + i] * ul[c][i];
        }
        uh[c][o][dp] = __floats2half2_rn(s0, s1);
      }
  }

  float blog[2][5];
#pragma unroll
  for (int c = 0; c < 2; ++c)
#pragma unroll
    for (int o = 0; o < 5; ++o) blog[c][o] = 0.f;

  for (int it = 0; it < 3; ++it) {
    float spart[80];
#pragma unroll
    for (int j = 0; j < 80; ++j) spart[j] = 0.f;
#pragma unroll
    for (int c = 0; c < 2; ++c) {
      float m = blog[c][0];
#pragma unroll
      for (int o = 1; o < 5; ++o) m = fmaxf(m, blog[c][o]);
      float e[5], es = 0.f;
#pragma unroll
      for (int o = 0; o < 5; ++o) { e[o] = __expf(blog[c][o] - m); es += e[o]; }
      const float inv = 1.f / es;
#pragma unroll
      for (int o = 0; o < 5; ++o) {
        const float cc = e[o] * inv;
#pragma unroll
        for (int dp = 0; dp < 8; ++dp) {
          const float2 f = __half22float2(uh[c][o][dp]);
          spart[o * 16 + dp * 2 + 0] += cc * f.x;
          spart[o * 16 + dp * 2 + 1] += cc * f.y;
        }
      }
    }
#pragma unroll
    for (int off = 32; off > 0; off >>= 1)
#pragma unroll
      for (int j = 0; j < 80; ++j) spart[j] += __shfl_xor(spart[j], off);
    if ((t & 63) == 0) {
      const int w = t >> 6;
#pragma unroll
      for (int j = 0; j < 80; ++j) red[w][j] = spart[j];
    }
    __syncthreads();
    if (t < 80) {
      const float s = red[0][t] + red[1][t] + red[2][t] + red[3][t];
      float sq = s * s;
      sq += __shfl_xor(sq, 1);
      sq += __shfl_xor(sq, 2);
      sq += __shfl_xor(sq, 4);
      sq += __shfl_xor(sq, 8);
      const float scale = sq / (1.f + sq) / sqrtf(sq + 1e-8f);
      const float v = s * scale;
      vsh[t] = v;
      if (it == 2) {
        out[5 * BSZ + (size_t)b * 80 + t] = v;
        float vv = v * v;
        vv += __shfl_xor(vv, 1);
        vv += __shfl_xor(vv, 2);
        vv += __shfl_xor(vv, 4);
        vv += __shfl_xor(vv, 8);
        if ((t & 15) == 0) out[(size_t)b * 5 + (t >> 4)] = sqrtf(vv);
      }
    }
    __syncthreads();
    if (it < 2) {
#pragma unroll
      for (int c = 0; c < 2; ++c)
#pragma unroll
        for (int o = 0; o < 5; ++o) {
          float ag = 0.f;
#pragma unroll
          for (int dp = 0; dp < 8; ++dp) {
            const float2 f = __half22float2(uh[c][o][dp]);
            ag += f.x * vsh[o * 16 + dp * 2] + f.y * vsh[o * 16 + dp * 2 + 1];
          }
          blog[c][o] += ag;
        }
    }
  }
}

// =====================================================================
extern "C" void kernel_launch(void* const* d_in, const int* in_sizes, int n_in,
                              void* d_out, int out_size, void* d_ws, size_t ws_size,
                              hipStream_t stream) {
  const float* x     = (const float*)d_in[0];
  const float* W1    = (const float*)d_in[1];
  const float* b1    = (const float*)d_in[2];
  const float* convW = (const float*)d_in[3];
  const float* convB = (const float*)d_in[4];
  const float* Wr    = (const float*)d_in[5];
  float* out = (float*)d_out;

  // workspace layout
  char* base = (char*)d_ws;
  size_t off = 0;
  auto alloc = [&](size_t bytes) { size_t o = off; off = (off + bytes + 255) & ~(size_t)255; return o; };
  const size_t o_h   = alloc((size_t)BSZ * PROJ * 2);        // 18.9 MB bf16
  const size_t o_w1t = alloc((size_t)PROJ * INDIM * 2);      // 14.2 MB bf16
  const size_t o_xb  = alloc((size_t)BSZ * INDIM * 2);       // 1.6 MB bf16
  const size_t o_wb  = alloc((size_t)256 * KPAD * 2);        // 1.6 MB bf16
  const size_t o_cv  = alloc((size_t)BSZ * 16 * 256 * 4);    // 16.8 MB f32
  const size_t o_u   = alloc((size_t)BSZ * 4096 * 2);        // 8.4 MB bf16
  const size_t o_bm  = off;                                  // chunked im2col buffer

  int chunkB = 1024;
  while (chunkB > 8 && o_bm + (size_t)chunkB * 16 * KPAD * 2 > ws_size) chunkB >>= 1;

  unsigned short* h   = (unsigned short*)(base + o_h);
  unsigned short* w1t = (unsigned short*)(base + o_w1t);
  unsigned short* xb  = (unsigned short*)(base + o_xb);
  unsigned short* wb  = (unsigned short*)(base + o_wb);
  float*          cv  = (float*)(base + o_cv);
  unsigned short* u   = (unsigned short*)(base + o_u);
  unsigned short* bm  = (unsigned short*)(base + o_bm);

  convert_x<<<BSZ * INDIM / 4 / 256, 256, 0, stream>>>(x, xb);
  transpose_w1<<<dim3(PROJ / 32, INDIM / 32), 256, 0, stream>>>(W1, w1t);
  convw_prep<<<256, 256, 0, stream>>>(convW, wb);

  // h = relu(x @ W1 + b1)
  mfma_gemm<1, 1><<<dim3(PROJ / 128, BSZ / 128), 256, 0, stream>>>(
      xb, w1t, b1, (void*)h, BSZ, PROJ, INDIM);

  // conv as chunked im2col GEMM
  for (int b0 = 0; b0 < BSZ; b0 += chunkB) {
    im2col<<<chunkB, 256, 0, stream>>>(h, bm, b0);
    mfma_gemm<0, 0><<<dim3(2, chunkB * 16 / 128), 256, 0, stream>>>(
        bm, wb, convB, (void*)(cv + (size_t)b0 * 16 * 256), chunkB * 16, 256, KPAD);
  }

  squash_u<<<BSZ, 256, 0, stream>>>(cv, u);
  routing<<<BSZ, 256, 0, stream>>>(u, Wr, out);
}

// Round 3
// 258.439 us; speedup vs baseline: 4.2649x; 1.9984x over previous
//
#include <hip/hip_runtime.h>
#include <hip/hip_fp16.h>

#define BSZ   1024
#define INDIM 768
#define PROJ  9216     // 256*6*6
#define NCAP  512
#define NCLS  5
#define KPAD  3072     // 256 ic * 12 (9 taps + 3 zero pad)

typedef __bf16 bf16x8 __attribute__((ext_vector_type(8)));
typedef float  f32x4  __attribute__((ext_vector_type(4)));

static __device__ __forceinline__ unsigned short f2bf(float f) {
  unsigned int x = __float_as_uint(f);
  return (unsigned short)((x + 0x7fffu + ((x >> 16) & 1u)) >> 16);
}
static __device__ __forceinline__ float bf2f(unsigned int u) {
  return __uint_as_float(u << 16);
}

// global -> LDS direct (16B per lane)
static __device__ __forceinline__ void gload16(const void* g, void* l) {
  auto gp = reinterpret_cast<const unsigned int __attribute__((address_space(1)))*>(
      (unsigned long long)g);
  auto lp = reinterpret_cast<unsigned int __attribute__((address_space(3)))*>(
      (unsigned long long)l);
  __builtin_amdgcn_global_load_lds(gp, lp, 16, 0, 0);
}

// =====================================================================
// Unified bf16 MFMA GEMM: C[M][N] = A[M][K] * Bt[N][K]^T + bias[N]
// (unchanged from R2 — passing)
// =====================================================================
template <int RELU, int OBF16>
__global__ __launch_bounds__(256) void mfma_gemm(
    const unsigned short* __restrict__ A,   // [M][K] bf16
    const unsigned short* __restrict__ Bt,  // [N][K] bf16
    const float* __restrict__ bias,         // [N]
    void* __restrict__ Cout,                // [M][N] f32 or bf16
    int M, int N, int K) {
  __shared__ __align__(16) unsigned short smem[16384];
  const int t    = threadIdx.x;
  const int bn   = blockIdx.x * 128;
  const int bm   = blockIdx.y * 128;
  const int lane = t & 63;
  const int wid  = t >> 6;
  const int wm   = (wid >> 1) * 64;
  const int wn   = (wid & 1) * 64;
  const int l15  = lane & 15;
  const int kb   = lane >> 4;

  const int r0 = t >> 2,         kc = t & 3;
  const int r1 = (t + 256) >> 2;
  const int gk0 = ((kc ^ (r0 & 3)) << 3);
  const int gk1 = ((kc ^ (r1 & 3)) << 3);

  const unsigned short* Ar0 = A  + (size_t)(bm + r0) * K + gk0;
  const unsigned short* Ar1 = A  + (size_t)(bm + r1) * K + gk1;
  const unsigned short* Br0 = Bt + (size_t)(bn + r0) * K + gk0;
  const unsigned short* Br1 = Bt + (size_t)(bn + r1) * K + gk1;

  int aoff[4], boff[4];
#pragma unroll
  for (int i = 0; i < 4; ++i) {
    const int ra = wm + i * 16 + l15;
    aoff[i] = ra * 32 + ((kb ^ (ra & 3)) << 3);
    const int rb = wn + i * 16 + l15;
    boff[i] = 4096 + rb * 32 + ((kb ^ (rb & 3)) << 3);
  }

  f32x4 acc[4][4];
#pragma unroll
  for (int i = 0; i < 4; ++i)
#pragma unroll
    for (int j = 0; j < 4; ++j)
#pragma unroll
      for (int q = 0; q < 4; ++q) acc[i][j][q] = 0.f;

  const int nk = K >> 5;
  gload16(Ar0, &smem[t * 8]);
  gload16(Ar1, &smem[(t + 256) * 8]);
  gload16(Br0, &smem[4096 + t * 8]);
  gload16(Br1, &smem[4096 + (t + 256) * 8]);
  __syncthreads();

  int buf = 0;
  for (int ks = 0; ks < nk; ++ks) {
    if (ks + 1 < nk) {
      const int k = (ks + 1) << 5;
      const int o = (buf ^ 1) * 8192;
      gload16(Ar0 + k, &smem[o + t * 8]);
      gload16(Ar1 + k, &smem[o + (t + 256) * 8]);
      gload16(Br0 + k, &smem[o + 4096 + t * 8]);
      gload16(Br1 + k, &smem[o + 4096 + (t + 256) * 8]);
    }
    const unsigned short* base = &smem[buf * 8192];
    bf16x8 af[4], bfr[4];
#pragma unroll
    for (int i = 0; i < 4; ++i) {
      af[i]  = *(const bf16x8*)(base + aoff[i]);
      bfr[i] = *(const bf16x8*)(base + boff[i]);
    }
#pragma unroll
    for (int i = 0; i < 4; ++i)
#pragma unroll
      for (int j = 0; j < 4; ++j)
        acc[i][j] = __builtin_amdgcn_mfma_f32_16x16x32_bf16(af[i], bfr[j], acc[i][j], 0, 0, 0);
    __syncthreads();
    buf ^= 1;
  }

#pragma unroll
  for (int j = 0; j < 4; ++j) {
    const int col = bn + wn + j * 16 + l15;
    const float bv = bias[col];
#pragma unroll
    for (int i = 0; i < 4; ++i) {
#pragma unroll
      for (int q = 0; q < 4; ++q) {
        const int row = bm + wm + i * 16 + kb * 4 + q;
        float v = acc[i][j][q] + bv;
        if (RELU) v = fmaxf(v, 0.f);
        if (OBF16) ((unsigned short*)Cout)[(size_t)row * N + col] = f2bf(v);
        else       ((float*)Cout)[(size_t)row * N + col] = v;
      }
    }
  }
}

// =====================================================================
// Transforms
// =====================================================================
__global__ __launch_bounds__(256) void convert_bf16(const float* __restrict__ in,
                                                    unsigned short* __restrict__ out,
                                                    int n4) {
  const int i = blockIdx.x * 256 + threadIdx.x;
  if (i >= n4) return;
  float4 v = ((const float4*)in)[i];
  ushort4 o;
  o.x = f2bf(v.x); o.y = f2bf(v.y); o.z = f2bf(v.z); o.w = f2bf(v.w);
  ((ushort4*)out)[i] = o;
}

__global__ __launch_bounds__(256) void transpose_w1(const float* __restrict__ W,
                                                    unsigned short* __restrict__ Wt) {
  __shared__ float tile[32][33];
  const int n0 = blockIdx.x * 32, k0 = blockIdx.y * 32;
  const int r = threadIdx.x >> 3, c = (threadIdx.x & 7) * 4;
  float4 v = *(const float4*)(W + (size_t)(k0 + r) * PROJ + n0 + c);
  tile[r][c] = v.x; tile[r][c + 1] = v.y; tile[r][c + 2] = v.z; tile[r][c + 3] = v.w;
  __syncthreads();
  ushort4 o;
  o.x = f2bf(tile[c + 0][r]); o.y = f2bf(tile[c + 1][r]);
  o.z = f2bf(tile[c + 2][r]); o.w = f2bf(tile[c + 3][r]);
  *(ushort4*)(Wt + (size_t)(n0 + r) * INDIM + k0 + c) = o;
}

__global__ __launch_bounds__(256) void convw_prep(const float* __restrict__ W,
                                                  unsigned short* __restrict__ Wb) {
  const int id = blockIdx.x * 256 + threadIdx.x;
  const float* s = W + (size_t)id * 9;
  unsigned int v[9];
#pragma unroll
  for (int j = 0; j < 9; ++j) v[j] = f2bf(s[j]);
  uint2* d = (uint2*)(Wb + (size_t)id * 12);
  d[0] = make_uint2(v[0] | (v[1] << 16), v[2] | (v[3] << 16));
  d[1] = make_uint2(v[4] | (v[5] << 16), v[6] | (v[7] << 16));
  d[2] = make_uint2(v[8], 0u);
}

__global__ __launch_bounds__(256) void im2col(const unsigned short* __restrict__ H,
                                              unsigned short* __restrict__ Bm, int b0) {
  __shared__ unsigned int rowbuf[1536];
  const int b = b0 + blockIdx.x;
  const int t = threadIdx.x;  // = ic
  unsigned int hu[18];
  const uint2* src = (const uint2*)(H + (size_t)b * PROJ + t * 36);
#pragma unroll
  for (int j = 0; j < 9; ++j) { uint2 q = src[j]; hu[2 * j] = q.x; hu[2 * j + 1] = q.y; }
#pragma unroll
  for (int p = 0; p < 16; ++p) {
    const int pi = p >> 2, pj = p & 3;
    unsigned int v[9];
#pragma unroll
    for (int r = 0; r < 9; ++r) {
      const int j = (pi + r / 3) * 6 + pj + (r % 3);
      v[r] = (hu[j >> 1] >> ((j & 1) * 16)) & 0xffffu;
    }
    if (p) __syncthreads();
    rowbuf[t * 6 + 0] = v[0] | (v[1] << 16);
    rowbuf[t * 6 + 1] = v[2] | (v[3] << 16);
    rowbuf[t * 6 + 2] = v[4] | (v[5] << 16);
    rowbuf[t * 6 + 3] = v[6] | (v[7] << 16);
    rowbuf[t * 6 + 4] = v[8];
    rowbuf[t * 6 + 5] = 0u;
    __syncthreads();
    uint2* dst = (uint2*)(Bm + ((size_t)blockIdx.x * 16 + p) * KPAD);
    const uint2* rb = (const uint2*)rowbuf;
#pragma unroll
    for (int j = 0; j < 3; ++j) dst[t + j * 256] = rb[t + j * 256];
  }
}

__global__ __launch_bounds__(256) void squash_u(const float* __restrict__ cv,
                                                unsigned short* __restrict__ U) {
  const int b = blockIdx.x;
  const int t = threadIdx.x;
#pragma unroll
  for (int h = 0; h < 2; ++h) {
    const int id = t + h * 256;
    const int cap = id & 31, p = id >> 5;
    const float* s = cv + ((size_t)b * 16 + p) * 256 + cap * 8;
    float4 a = *(const float4*)s;
    float4 c = *(const float4*)(s + 4);
    float sq = a.x * a.x + a.y * a.y + a.z * a.z + a.w * a.w +
               c.x * c.x + c.y * c.y + c.z * c.z + c.w * c.w;
    const float scale = sq / (1.f + sq) / sqrtf(sq + 1e-8f);
    unsigned short* d = U + (size_t)b * 4096 + cap * 128 + p * 8;
    ushort4 o0, o1;
    o0.x = f2bf(a.x * scale); o0.y = f2bf(a.y * scale);
    o0.z = f2bf(a.z * scale); o0.w = f2bf(a.w * scale);
    o1.x = f2bf(c.x * scale); o1.y = f2bf(c.y * scale);
    o1.z = f2bf(c.z * scale); o1.w = f2bf(c.w * scale);
    *(ushort4*)d = o0; *(ushort4*)(d + 4) = o1;
  }
}

// =====================================================================
// Routing v2: one block (512 threads) per batch element.
// u_hat[512][80] lives in LDS as fp16 (row pad to 82 -> odd word stride).
// No shfl butterflies; all reductions via LDS with conflict-free layouts.
// =====================================================================
__global__ __launch_bounds__(512, 1) void routing2(
    const unsigned short* __restrict__ U,    // [b][512][8] bf16
    const unsigned short* __restrict__ Wrb,  // [512][5][16][8] bf16
    float* __restrict__ out) {
  __shared__ __half uhat[NCAP * 82];   // 83,968 B
  __shared__ float carr[NCAP * 5];     // 10,240 B
  __shared__ float sred[6 * 80];
  __shared__ float vsh[80];
  const int b = blockIdx.x;
  const int t = threadIdx.x;  // capsule index n

  // ---- load u[n] (8 bf16) ----
  float ul[8];
  {
    uint4 q = *(const uint4*)(U + (size_t)b * 4096 + t * 8);
    ul[0] = bf2f(q.x & 0xffffu); ul[1] = bf2f(q.x >> 16);
    ul[2] = bf2f(q.y & 0xffffu); ul[3] = bf2f(q.y >> 16);
    ul[4] = bf2f(q.z & 0xffffu); ul[5] = bf2f(q.z >> 16);
    ul[6] = bf2f(q.w & 0xffffu); ul[7] = bf2f(q.w >> 16);
  }

  // ---- u_hat[n][o*16+d] -> LDS fp16 (word = o*8+dp, d = 2dp,2dp+1) ----
  {
    const unsigned short* wp = Wrb + (size_t)t * 640;
    __half2* urow = ((__half2*)uhat) + t * 41;
#pragma unroll
    for (int o = 0; o < 5; ++o)
#pragma unroll
      for (int dp = 0; dp < 8; ++dp) {
        const uint4 wa = *(const uint4*)(wp + o * 128 + dp * 16);
        const uint4 wc = *(const uint4*)(wp + o * 128 + dp * 16 + 8);
        float s0 = bf2f(wa.x & 0xffffu) * ul[0] + bf2f(wa.x >> 16) * ul[1]
                 + bf2f(wa.y & 0xffffu) * ul[2] + bf2f(wa.y >> 16) * ul[3]
                 + bf2f(wa.z & 0xffffu) * ul[4] + bf2f(wa.z >> 16) * ul[5]
                 + bf2f(wa.w & 0xffffu) * ul[6] + bf2f(wa.w >> 16) * ul[7];
        float s1 = bf2f(wc.x & 0xffffu) * ul[0] + bf2f(wc.x >> 16) * ul[1]
                 + bf2f(wc.y & 0xffffu) * ul[2] + bf2f(wc.y >> 16) * ul[3]
                 + bf2f(wc.z & 0xffffu) * ul[4] + bf2f(wc.z >> 16) * ul[5]
                 + bf2f(wc.w & 0xffffu) * ul[6] + bf2f(wc.w >> 16) * ul[7];
        urow[o * 8 + dp] = __floats2half2_rn(s0, s1);
      }
  }

  float blog[5];
#pragma unroll
  for (int o = 0; o < 5; ++o) blog[o] = 0.f;

  const int od  = t % 80;      // s-phase ownership
  const int seg = t / 80;      // 0..6 (seg 6 = threads 480..511, idle)
  const int n0  = seg * 86;
  const int n1  = (seg == 5) ? 512 : n0 + 86;

  for (int it = 0; it < 3; ++it) {
    // softmax c[n][o] from blog (this thread owns capsule n=t)
    {
      float m = blog[0];
#pragma unroll
      for (int o = 1; o < 5; ++o) m = fmaxf(m, blog[o]);
      float e[5], es = 0.f;
#pragma unroll
      for (int o = 0; o < 5; ++o) { e[o] = __expf(blog[o] - m); es += e[o]; }
      const float inv = 1.f / es;
#pragma unroll
      for (int o = 0; o < 5; ++o) carr[t * 5 + o] = e[o] * inv;
    }
    __syncthreads();

    // s[od] partial over capsule segment
    if (t < 480) {
      const int oq = od >> 4;
      float acc = 0.f;
      for (int n = n0; n < n1; ++n)
        acc += carr[n * 5 + oq] * __half2float(uhat[n * 82 + od]);
      sred[seg * 80 + od] = acc;
    }
    __syncthreads();

    // combine + squash + v
    if (t < 80) {
      float s = sred[t] + sred[80 + t] + sred[160 + t] +
                sred[240 + t] + sred[320 + t] + sred[400 + t];
      float sq = s * s;
      sq += __shfl_xor(sq, 1);
      sq += __shfl_xor(sq, 2);
      sq += __shfl_xor(sq, 4);
      sq += __shfl_xor(sq, 8);
      const float scale = sq / (1.f + sq) / sqrtf(sq + 1e-8f);
      const float v = s * scale;
      vsh[t] = v;
      if (it == 2) {
        out[5 * BSZ + (size_t)b * 80 + t] = v;
        float vv = v * v;
        vv += __shfl_xor(vv, 1);
        vv += __shfl_xor(vv, 2);
        vv += __shfl_xor(vv, 4);
        vv += __shfl_xor(vv, 8);
        if ((t & 15) == 0) out[(size_t)b * 5 + (t >> 4)] = sqrtf(vv);
      }
    }
    __syncthreads();

    // agreement: blog[o] += u_hat[n=t][o,:] . v[o,:]
    if (it < 2) {
      const __half2* urow = ((const __half2*)uhat) + t * 41;
#pragma unroll
      for (int o = 0; o < 5; ++o) {
        float ag = 0.f;
#pragma unroll
        for (int w = 0; w < 8; ++w) {
          const float2 f = __half22float2(urow[o * 8 + w]);
          ag += f.x * vsh[o * 16 + 2 * w] + f.y * vsh[o * 16 + 2 * w + 1];
        }
        blog[o] += ag;
      }
    }
  }
}

// =====================================================================
extern "C" void kernel_launch(void* const* d_in, const int* in_sizes, int n_in,
                              void* d_out, int out_size, void* d_ws, size_t ws_size,
                              hipStream_t stream) {
  const float* x     = (const float*)d_in[0];
  const float* W1    = (const float*)d_in[1];
  const float* b1    = (const float*)d_in[2];
  const float* convW = (const float*)d_in[3];
  const float* convB = (const float*)d_in[4];
  const float* Wr    = (const float*)d_in[5];
  float* out = (float*)d_out;

  char* base = (char*)d_ws;
  size_t off = 0;
  auto alloc = [&](size_t bytes) { size_t o = off; off = (off + bytes + 255) & ~(size_t)255; return o; };
  const size_t o_h   = alloc((size_t)BSZ * PROJ * 2);        // 18.9 MB bf16
  const size_t o_w1t = alloc((size_t)PROJ * INDIM * 2);      // 14.2 MB bf16
  const size_t o_xb  = alloc((size_t)BSZ * INDIM * 2);       // 1.6 MB bf16
  const size_t o_wb  = alloc((size_t)256 * KPAD * 2);        // 1.6 MB bf16
  const size_t o_wrb = alloc((size_t)NCAP * 640 * 2);        // 0.66 MB bf16
  const size_t o_cv  = alloc((size_t)BSZ * 16 * 256 * 4);    // 16.8 MB f32
  const size_t o_u   = alloc((size_t)BSZ * 4096 * 2);        // 8.4 MB bf16
  const size_t o_bm  = off;

  int chunkB = 1024;
  while (chunkB > 8 && o_bm + (size_t)chunkB * 16 * KPAD * 2 > ws_size) chunkB >>= 1;

  unsigned short* h   = (unsigned short*)(base + o_h);
  unsigned short* w1t = (unsigned short*)(base + o_w1t);
  unsigned short* xb  = (unsigned short*)(base + o_xb);
  unsigned short* wb  = (unsigned short*)(base + o_wb);
  unsigned short* wrb = (unsigned short*)(base + o_wrb);
  float*          cv  = (float*)(base + o_cv);
  unsigned short* u   = (unsigned short*)(base + o_u);
  unsigned short* bm  = (unsigned short*)(base + o_bm);

  convert_bf16<<<(BSZ * INDIM / 4 + 255) / 256, 256, 0, stream>>>(x, xb, BSZ * INDIM / 4);
  transpose_w1<<<dim3(PROJ / 32, INDIM / 32), 256, 0, stream>>>(W1, w1t);
  convw_prep<<<256, 256, 0, stream>>>(convW, wb);
  convert_bf16<<<(NCAP * 640 / 4 + 255) / 256, 256, 0, stream>>>(Wr, wrb, NCAP * 640 / 4);

  mfma_gemm<1, 1><<<dim3(PROJ / 128, BSZ / 128), 256, 0, stream>>>(
      xb, w1t, b1, (void*)h, BSZ, PROJ, INDIM);

  for (int b0 = 0; b0 < BSZ; b0 += chunkB) {
    im2col<<<chunkB, 256, 0, stream>>>(h, bm, b0);
    mfma_gemm<0, 0><<<dim3(2, chunkB * 16 / 128), 256, 0, stream>>>(
        bm, wb, convB, (void*)(cv + (size_t)b0 * 16 * 256), chunkB * 16, 256, KPAD);
  }

  squash_u<<<BSZ, 256, 0, stream>>>(cv, u);
  routing2<<<BSZ, 512, 0, stream>>>(u, wrb, out);
}

// Round 4
// 249.776 us; speedup vs baseline: 4.4128x; 1.0347x over previous
//
#include <hip/hip_runtime.h>
#include <hip/hip_fp16.h>

#define BSZ   1024
#define INDIM 768
#define PROJ  9216     // 256*6*6
#define NCAP  512
#define NCLS  5
#define KPAD  3072     // 256 ic * 12 (9 taps + 3 zero pad)

typedef __bf16    bf16x8 __attribute__((ext_vector_type(8)));
typedef float     f32x4  __attribute__((ext_vector_type(4)));
typedef _Float16  h2     __attribute__((ext_vector_type(2)));

static __device__ __forceinline__ unsigned short f2bf(float f) {
  unsigned int x = __float_as_uint(f);
  return (unsigned short)((x + 0x7fffu + ((x >> 16) & 1u)) >> 16);
}
static __device__ __forceinline__ float bf2f(unsigned int u) {
  return __uint_as_float(u << 16);
}

#if defined(__has_builtin)
#if __has_builtin(__builtin_amdgcn_fdot2)
#define HAVE_FDOT2 1
#endif
#endif
static __device__ __forceinline__ float fdot2(h2 a, h2 b, float c) {
#ifdef HAVE_FDOT2
  return __builtin_amdgcn_fdot2(a, b, c, false);
#else
  return c + (float)a[0] * (float)b[0] + (float)a[1] * (float)b[1];
#endif
}
static __device__ __forceinline__ h2 u2h2(unsigned int u) {
  return __builtin_bit_cast(h2, u);
}

// global -> LDS direct (16B per lane)
static __device__ __forceinline__ void gload16(const void* g, void* l) {
  auto gp = reinterpret_cast<const unsigned int __attribute__((address_space(1)))*>(
      (unsigned long long)g);
  auto lp = reinterpret_cast<unsigned int __attribute__((address_space(3)))*>(
      (unsigned long long)l);
  __builtin_amdgcn_global_load_lds(gp, lp, 16, 0, 0);
}

// =====================================================================
// Unified bf16 MFMA GEMM (unchanged — passing)
// =====================================================================
template <int RELU, int OBF16>
__global__ __launch_bounds__(256) void mfma_gemm(
    const unsigned short* __restrict__ A,   // [M][K] bf16
    const unsigned short* __restrict__ Bt,  // [N][K] bf16
    const float* __restrict__ bias,         // [N]
    void* __restrict__ Cout,                // [M][N] f32 or bf16
    int M, int N, int K) {
  __shared__ __align__(16) unsigned short smem[16384];
  const int t    = threadIdx.x;
  const int bn   = blockIdx.x * 128;
  const int bm   = blockIdx.y * 128;
  const int lane = t & 63;
  const int wid  = t >> 6;
  const int wm   = (wid >> 1) * 64;
  const int wn   = (wid & 1) * 64;
  const int l15  = lane & 15;
  const int kb   = lane >> 4;

  const int r0 = t >> 2,         kc = t & 3;
  const int r1 = (t + 256) >> 2;
  const int gk0 = ((kc ^ (r0 & 3)) << 3);
  const int gk1 = ((kc ^ (r1 & 3)) << 3);

  const unsigned short* Ar0 = A  + (size_t)(bm + r0) * K + gk0;
  const unsigned short* Ar1 = A  + (size_t)(bm + r1) * K + gk1;
  const unsigned short* Br0 = Bt + (size_t)(bn + r0) * K + gk0;
  const unsigned short* Br1 = Bt + (size_t)(bn + r1) * K + gk1;

  int aoff[4], boff[4];
#pragma unroll
  for (int i = 0; i < 4; ++i) {
    const int ra = wm + i * 16 + l15;
    aoff[i] = ra * 32 + ((kb ^ (ra & 3)) << 3);
    const int rb = wn + i * 16 + l15;
    boff[i] = 4096 + rb * 32 + ((kb ^ (rb & 3)) << 3);
  }

  f32x4 acc[4][4];
#pragma unroll
  for (int i = 0; i < 4; ++i)
#pragma unroll
    for (int j = 0; j < 4; ++j)
#pragma unroll
      for (int q = 0; q < 4; ++q) acc[i][j][q] = 0.f;

  const int nk = K >> 5;
  gload16(Ar0, &smem[t * 8]);
  gload16(Ar1, &smem[(t + 256) * 8]);
  gload16(Br0, &smem[4096 + t * 8]);
  gload16(Br1, &smem[4096 + (t + 256) * 8]);
  __syncthreads();

  int buf = 0;
  for (int ks = 0; ks < nk; ++ks) {
    if (ks + 1 < nk) {
      const int k = (ks + 1) << 5;
      const int o = (buf ^ 1) * 8192;
      gload16(Ar0 + k, &smem[o + t * 8]);
      gload16(Ar1 + k, &smem[o + (t + 256) * 8]);
      gload16(Br0 + k, &smem[o + 4096 + t * 8]);
      gload16(Br1 + k, &smem[o + 4096 + (t + 256) * 8]);
    }
    const unsigned short* base = &smem[buf * 8192];
    bf16x8 af[4], bfr[4];
#pragma unroll
    for (int i = 0; i < 4; ++i) {
      af[i]  = *(const bf16x8*)(base + aoff[i]);
      bfr[i] = *(const bf16x8*)(base + boff[i]);
    }
#pragma unroll
    for (int i = 0; i < 4; ++i)
#pragma unroll
      for (int j = 0; j < 4; ++j)
        acc[i][j] = __builtin_amdgcn_mfma_f32_16x16x32_bf16(af[i], bfr[j], acc[i][j], 0, 0, 0);
    __syncthreads();
    buf ^= 1;
  }

#pragma unroll
  for (int j = 0; j < 4; ++j) {
    const int col = bn + wn + j * 16 + l15;
    const float bv = bias[col];
#pragma unroll
    for (int i = 0; i < 4; ++i) {
#pragma unroll
      for (int q = 0; q < 4; ++q) {
        const int row = bm + wm + i * 16 + kb * 4 + q;
        float v = acc[i][j][q] + bv;
        if (RELU) v = fmaxf(v, 0.f);
        if (OBF16) ((unsigned short*)Cout)[(size_t)row * N + col] = f2bf(v);
        else       ((float*)Cout)[(size_t)row * N + col] = v;
      }
    }
  }
}

// =====================================================================
// Transforms
// =====================================================================
__global__ __launch_bounds__(256) void convert_bf16(const float* __restrict__ in,
                                                    unsigned short* __restrict__ out,
                                                    int n4) {
  const int i = blockIdx.x * 256 + threadIdx.x;
  if (i >= n4) return;
  float4 v = ((const float4*)in)[i];
  ushort4 o;
  o.x = f2bf(v.x); o.y = f2bf(v.y); o.z = f2bf(v.z); o.w = f2bf(v.w);
  ((ushort4*)out)[i] = o;
}

__global__ __launch_bounds__(256) void convert_f16(const float* __restrict__ in,
                                                   __half2* __restrict__ out, int n4) {
  const int i = blockIdx.x * 256 + threadIdx.x;
  if (i >= n4) return;
  float4 v = ((const float4*)in)[i];
  out[i * 2]     = __floats2half2_rn(v.x, v.y);
  out[i * 2 + 1] = __floats2half2_rn(v.z, v.w);
}

__global__ __launch_bounds__(256) void transpose_w1(const float* __restrict__ W,
                                                    unsigned short* __restrict__ Wt) {
  __shared__ float tile[32][33];
  const int n0 = blockIdx.x * 32, k0 = blockIdx.y * 32;
  const int r = threadIdx.x >> 3, c = (threadIdx.x & 7) * 4;
  float4 v = *(const float4*)(W + (size_t)(k0 + r) * PROJ + n0 + c);
  tile[r][c] = v.x; tile[r][c + 1] = v.y; tile[r][c + 2] = v.z; tile[r][c + 3] = v.w;
  __syncthreads();
  ushort4 o;
  o.x = f2bf(tile[c + 0][r]); o.y = f2bf(tile[c + 1][r]);
  o.z = f2bf(tile[c + 2][r]); o.w = f2bf(tile[c + 3][r]);
  *(ushort4*)(Wt + (size_t)(n0 + r) * INDIM + k0 + c) = o;
}

__global__ __launch_bounds__(256) void convw_prep(const float* __restrict__ W,
                                                  unsigned short* __restrict__ Wb) {
  const int id = blockIdx.x * 256 + threadIdx.x;
  const float* s = W + (size_t)id * 9;
  unsigned int v[9];
#pragma unroll
  for (int j = 0; j < 9; ++j) v[j] = f2bf(s[j]);
  uint2* d = (uint2*)(Wb + (size_t)id * 12);
  d[0] = make_uint2(v[0] | (v[1] << 16), v[2] | (v[3] << 16));
  d[1] = make_uint2(v[4] | (v[5] << 16), v[6] | (v[7] << 16));
  d[2] = make_uint2(v[8], 0u);
}

__global__ __launch_bounds__(256) void im2col(const unsigned short* __restrict__ H,
                                              unsigned short* __restrict__ Bm, int b0) {
  __shared__ unsigned int rowbuf[1536];
  const int b = b0 + blockIdx.x;
  const int t = threadIdx.x;  // = ic
  unsigned int hu[18];
  const uint2* src = (const uint2*)(H + (size_t)b * PROJ + t * 36);
#pragma unroll
  for (int j = 0; j < 9; ++j) { uint2 q = src[j]; hu[2 * j] = q.x; hu[2 * j + 1] = q.y; }
#pragma unroll
  for (int p = 0; p < 16; ++p) {
    const int pi = p >> 2, pj = p & 3;
    unsigned int v[9];
#pragma unroll
    for (int r = 0; r < 9; ++r) {
      const int j = (pi + r / 3) * 6 + pj + (r % 3);
      v[r] = (hu[j >> 1] >> ((j & 1) * 16)) & 0xffffu;
    }
    if (p) __syncthreads();
    rowbuf[t * 6 + 0] = v[0] | (v[1] << 16);
    rowbuf[t * 6 + 1] = v[2] | (v[3] << 16);
    rowbuf[t * 6 + 2] = v[4] | (v[5] << 16);
    rowbuf[t * 6 + 3] = v[6] | (v[7] << 16);
    rowbuf[t * 6 + 4] = v[8];
    rowbuf[t * 6 + 5] = 0u;
    __syncthreads();
    uint2* dst = (uint2*)(Bm + ((size_t)blockIdx.x * 16 + p) * KPAD);
    const uint2* rb = (const uint2*)rowbuf;
#pragma unroll
    for (int j = 0; j < 3; ++j) dst[t + j * 256] = rb[t + j * 256];
  }
}

// squash -> U stored fp16 now
__global__ __launch_bounds__(256) void squash_u(const float* __restrict__ cv,
                                                __half2* __restrict__ U) {
  const int b = blockIdx.x;
  const int t = threadIdx.x;
#pragma unroll
  for (int h = 0; h < 2; ++h) {
    const int id = t + h * 256;
    const int cap = id & 31, p = id >> 5;
    const float* s = cv + ((size_t)b * 16 + p) * 256 + cap * 8;
    float4 a = *(const float4*)s;
    float4 c = *(const float4*)(s + 4);
    float sq = a.x * a.x + a.y * a.y + a.z * a.z + a.w * a.w +
               c.x * c.x + c.y * c.y + c.z * c.z + c.w * c.w;
    const float scale = sq / (1.f + sq) / sqrtf(sq + 1e-8f);
    __half2* d = U + ((size_t)b * 4096 + cap * 128 + p * 8) / 2;
    d[0] = __floats2half2_rn(a.x * scale, a.y * scale);
    d[1] = __floats2half2_rn(a.z * scale, a.w * scale);
    d[2] = __floats2half2_rn(c.x * scale, c.y * scale);
    d[3] = __floats2half2_rn(c.z * scale, c.w * scale);
  }
}

// =====================================================================
// Routing v3: 1024 threads per block, one batch element per block.
// u_hat via v_dot2_f32_f16; u_hat fp16 in LDS [512][82]; no butterflies.
// =====================================================================
__global__ __launch_bounds__(1024, 1) void routing3(
    const unsigned short* __restrict__ U,    // [b][512][8] fp16
    const unsigned short* __restrict__ Wrh,  // [512][5][16][8] fp16
    float* __restrict__ out) {
  __shared__ __half uhat[NCAP * 82];   // 83,968 B
  __shared__ float carr[NCAP * 5];     // 10,240 B
  __shared__ float sred[12 * 80];
  __shared__ __half2 vsh2[40];
  const int b = blockIdx.x;
  const int t = threadIdx.x;

  // ---- phase A: u_hat, 2 threads per capsule (n = t>>1, half = t&1) ----
  {
    const int n = t >> 1, half = t & 1;
    h2 ul[4];
    {
      uint4 q = *(const uint4*)(U + (size_t)b * 4096 + n * 8);
      ul[0] = u2h2(q.x); ul[1] = u2h2(q.y); ul[2] = u2h2(q.z); ul[3] = u2h2(q.w);
    }
    const unsigned short* wp = Wrh + (size_t)n * 640 + half * 320;
    __half2* urow = ((__half2*)uhat) + n * 41 + half * 20;
#pragma unroll
    for (int j = 0; j < 20; ++j) {
      const uint4 wa = *(const uint4*)(wp + j * 16);
      const uint4 wc = *(const uint4*)(wp + j * 16 + 8);
      float s0 = fdot2(u2h2(wa.w), ul[3],
                 fdot2(u2h2(wa.z), ul[2],
                 fdot2(u2h2(wa.y), ul[1],
                 fdot2(u2h2(wa.x), ul[0], 0.f))));
      float s1 = fdot2(u2h2(wc.w), ul[3],
                 fdot2(u2h2(wc.z), ul[2],
                 fdot2(u2h2(wc.y), ul[1],
                 fdot2(u2h2(wc.x), ul[0], 0.f))));
      urow[j] = __floats2half2_rn(s0, s1);
    }
  }

  float blog[5];
#pragma unroll
  for (int o = 0; o < 5; ++o) blog[o] = 0.f;

  const int od  = t % 80;
  const int seg = t / 80;                    // 0..12 (seg 12 partial -> idle)
  const int n0  = seg * 43;
  const int n1  = (n0 + 43 > 512) ? 512 : n0 + 43;

  for (int it = 0; it < 3; ++it) {
    // softmax c[n=t][o]
    if (t < NCAP) {
      float m = blog[0];
#pragma unroll
      for (int o = 1; o < 5; ++o) m = fmaxf(m, blog[o]);
      float e[5], es = 0.f;
#pragma unroll
      for (int o = 0; o < 5; ++o) { e[o] = __expf(blog[o] - m); es += e[o]; }
      const float inv = 1.f / es;
#pragma unroll
      for (int o = 0; o < 5; ++o) carr[t * 5 + o] = e[o] * inv;
    }
    __syncthreads();

    // s partials
    if (t < 960) {
      const int oq = od >> 4;
      float acc = 0.f;
      for (int n = n0; n < n1; ++n)
        acc += carr[n * 5 + oq] * __half2float(uhat[n * 82 + od]);
      sred[seg * 80 + od] = acc;
    }
    __syncthreads();

    // combine + squash + v (fp16 broadcast copy)
    if (t < 80) {
      float s = 0.f;
#pragma unroll
      for (int g = 0; g < 12; ++g) s += sred[g * 80 + t];
      float sq = s * s;
      sq += __shfl_xor(sq, 1);
      sq += __shfl_xor(sq, 2);
      sq += __shfl_xor(sq, 4);
      sq += __shfl_xor(sq, 8);
      const float scale = sq / (1.f + sq) / sqrtf(sq + 1e-8f);
      const float v = s * scale;
      const float vnext = __shfl_down(v, 1);
      if ((t & 1) == 0) vsh2[t >> 1] = __floats2half2_rn(v, vnext);
      if (it == 2) {
        out[5 * BSZ + (size_t)b * 80 + t] = v;
        float vv = v * v;
        vv += __shfl_xor(vv, 1);
        vv += __shfl_xor(vv, 2);
        vv += __shfl_xor(vv, 4);
        vv += __shfl_xor(vv, 8);
        if ((t & 15) == 0) out[(size_t)b * 5 + (t >> 4)] = sqrtf(vv);
      }
    }
    __syncthreads();

    // agreement via fdot2 against fp16 v
    if (it < 2 && t < NCAP) {
      const __half2* urow = ((const __half2*)uhat) + t * 41;
#pragma unroll
      for (int o = 0; o < 5; ++o) {
        float ag = 0.f;
#pragma unroll
        for (int w = 0; w < 8; ++w)
          ag = fdot2(__builtin_bit_cast(h2, urow[o * 8 + w]),
                     __builtin_bit_cast(h2, vsh2[o * 8 + w]), ag);
        blog[o] += ag;
      }
    }
  }
}

// =====================================================================
extern "C" void kernel_launch(void* const* d_in, const int* in_sizes, int n_in,
                              void* d_out, int out_size, void* d_ws, size_t ws_size,
                              hipStream_t stream) {
  const float* x     = (const float*)d_in[0];
  const float* W1    = (const float*)d_in[1];
  const float* b1    = (const float*)d_in[2];
  const float* convW = (const float*)d_in[3];
  const float* convB = (const float*)d_in[4];
  const float* Wr    = (const float*)d_in[5];
  float* out = (float*)d_out;

  char* base = (char*)d_ws;
  size_t off = 0;
  auto alloc = [&](size_t bytes) { size_t o = off; off = (off + bytes + 255) & ~(size_t)255; return o; };
  const size_t o_h   = alloc((size_t)BSZ * PROJ * 2);        // 18.9 MB bf16
  const size_t o_w1t = alloc((size_t)PROJ * INDIM * 2);      // 14.2 MB bf16
  const size_t o_xb  = alloc((size_t)BSZ * INDIM * 2);       // 1.6 MB bf16
  const size_t o_wb  = alloc((size_t)256 * KPAD * 2);        // 1.6 MB bf16
  const size_t o_wrh = alloc((size_t)NCAP * 640 * 2);        // 0.66 MB fp16
  const size_t o_cv  = alloc((size_t)BSZ * 16 * 256 * 4);    // 16.8 MB f32
  const size_t o_u   = alloc((size_t)BSZ * 4096 * 2);        // 8.4 MB fp16
  const size_t o_bm  = off;

  int chunkB = 1024;
  while (chunkB > 8 && o_bm + (size_t)chunkB * 16 * KPAD * 2 > ws_size) chunkB >>= 1;

  unsigned short* h   = (unsigned short*)(base + o_h);
  unsigned short* w1t = (unsigned short*)(base + o_w1t);
  unsigned short* xb  = (unsigned short*)(base + o_xb);
  unsigned short* wb  = (unsigned short*)(base + o_wb);
  unsigned short* wrh = (unsigned short*)(base + o_wrh);
  float*          cv  = (float*)(base + o_cv);
  __half2*        u   = (__half2*)(base + o_u);
  unsigned short* bm  = (unsigned short*)(base + o_bm);

  convert_bf16<<<(BSZ * INDIM / 4 + 255) / 256, 256, 0, stream>>>(x, xb, BSZ * INDIM / 4);
  transpose_w1<<<dim3(PROJ / 32, INDIM / 32), 256, 0, stream>>>(W1, w1t);
  convw_prep<<<256, 256, 0, stream>>>(convW, wb);
  convert_f16<<<(NCAP * 640 / 4 + 255) / 256, 256, 0, stream>>>(Wr, (__half2*)wrh, NCAP * 640 / 4);

  mfma_gemm<1, 1><<<dim3(PROJ / 128, BSZ / 128), 256, 0, stream>>>(
      xb, w1t, b1, (void*)h, BSZ, PROJ, INDIM);

  for (int b0 = 0; b0 < BSZ; b0 += chunkB) {
    im2col<<<chunkB, 256, 0, stream>>>(h, bm, b0);
    mfma_gemm<0, 0><<<dim3(2, chunkB * 16 / 128), 256, 0, stream>>>(
        bm, wb, convB, (void*)(cv + (size_t)b0 * 16 * 256), chunkB * 16, 256, KPAD);
  }

  squash_u<<<BSZ, 256, 0, stream>>>(cv, u);
  routing3<<<BSZ, 1024, 0, stream>>>((const unsigned short*)u, wrh, out);
}

// Round 5
// 217.765 us; speedup vs baseline: 5.0614x; 1.1470x over previous
//
#include <hip/hip_runtime.h>
#include <hip/hip_fp16.h>

#define BSZ   1024
#define INDIM 768
#define PROJ  9216     // 256*6*6
#define NCAP  512
#define NCLS  5
#define KPAD  3072     // 256 ic * 12 (9 taps + 3 zero pad)

typedef __bf16    bf16x8 __attribute__((ext_vector_type(8)));
typedef _Float16  f16x8  __attribute__((ext_vector_type(8)));
typedef float     f32x4  __attribute__((ext_vector_type(4)));
typedef _Float16  h2     __attribute__((ext_vector_type(2)));

static __device__ __forceinline__ unsigned short f2bf(float f) {
  unsigned int x = __float_as_uint(f);
  return (unsigned short)((x + 0x7fffu + ((x >> 16) & 1u)) >> 16);
}
static __device__ __forceinline__ float bf2f(unsigned int u) {
  return __uint_as_float(u << 16);
}

#if defined(__has_builtin)
#if __has_builtin(__builtin_amdgcn_fdot2)
#define HAVE_FDOT2 1
#endif
#endif
static __device__ __forceinline__ float fdot2(h2 a, h2 b, float c) {
#ifdef HAVE_FDOT2
  return __builtin_amdgcn_fdot2(a, b, c, false);
#else
  return c + (float)a[0] * (float)b[0] + (float)a[1] * (float)b[1];
#endif
}
static __device__ __forceinline__ h2 u2h2(unsigned int u) {
  return __builtin_bit_cast(h2, u);
}

// global -> LDS direct (16B per lane)
static __device__ __forceinline__ void gload16(const void* g, void* l) {
  auto gp = reinterpret_cast<const unsigned int __attribute__((address_space(1)))*>(
      (unsigned long long)g);
  auto lp = reinterpret_cast<unsigned int __attribute__((address_space(3)))*>(
      (unsigned long long)l);
  __builtin_amdgcn_global_load_lds(gp, lp, 16, 0, 0);
}

// =====================================================================
// Unified bf16 MFMA GEMM (unchanged — passing)
// =====================================================================
template <int RELU, int OBF16>
__global__ __launch_bounds__(256) void mfma_gemm(
    const unsigned short* __restrict__ A,   // [M][K] bf16
    const unsigned short* __restrict__ Bt,  // [N][K] bf16
    const float* __restrict__ bias,         // [N]
    void* __restrict__ Cout,                // [M][N] f32 or bf16
    int M, int N, int K) {
  __shared__ __align__(16) unsigned short smem[16384];
  const int t    = threadIdx.x;
  const int bn   = blockIdx.x * 128;
  const int bm   = blockIdx.y * 128;
  const int lane = t & 63;
  const int wid  = t >> 6;
  const int wm   = (wid >> 1) * 64;
  const int wn   = (wid & 1) * 64;
  const int l15  = lane & 15;
  const int kb   = lane >> 4;

  const int r0 = t >> 2,         kc = t & 3;
  const int r1 = (t + 256) >> 2;
  const int gk0 = ((kc ^ (r0 & 3)) << 3);
  const int gk1 = ((kc ^ (r1 & 3)) << 3);

  const unsigned short* Ar0 = A  + (size_t)(bm + r0) * K + gk0;
  const unsigned short* Ar1 = A  + (size_t)(bm + r1) * K + gk1;
  const unsigned short* Br0 = Bt + (size_t)(bn + r0) * K + gk0;
  const unsigned short* Br1 = Bt + (size_t)(bn + r1) * K + gk1;

  int aoff[4], boff[4];
#pragma unroll
  for (int i = 0; i < 4; ++i) {
    const int ra = wm + i * 16 + l15;
    aoff[i] = ra * 32 + ((kb ^ (ra & 3)) << 3);
    const int rb = wn + i * 16 + l15;
    boff[i] = 4096 + rb * 32 + ((kb ^ (rb & 3)) << 3);
  }

  f32x4 acc[4][4];
#pragma unroll
  for (int i = 0; i < 4; ++i)
#pragma unroll
    for (int j = 0; j < 4; ++j)
#pragma unroll
      for (int q = 0; q < 4; ++q) acc[i][j][q] = 0.f;

  const int nk = K >> 5;
  gload16(Ar0, &smem[t * 8]);
  gload16(Ar1, &smem[(t + 256) * 8]);
  gload16(Br0, &smem[4096 + t * 8]);
  gload16(Br1, &smem[4096 + (t + 256) * 8]);
  __syncthreads();

  int buf = 0;
  for (int ks = 0; ks < nk; ++ks) {
    if (ks + 1 < nk) {
      const int k = (ks + 1) << 5;
      const int o = (buf ^ 1) * 8192;
      gload16(Ar0 + k, &smem[o + t * 8]);
      gload16(Ar1 + k, &smem[o + (t + 256) * 8]);
      gload16(Br0 + k, &smem[o + 4096 + t * 8]);
      gload16(Br1 + k, &smem[o + 4096 + (t + 256) * 8]);
    }
    const unsigned short* base = &smem[buf * 8192];
    bf16x8 af[4], bfr[4];
#pragma unroll
    for (int i = 0; i < 4; ++i) {
      af[i]  = *(const bf16x8*)(base + aoff[i]);
      bfr[i] = *(const bf16x8*)(base + boff[i]);
    }
#pragma unroll
    for (int i = 0; i < 4; ++i)
#pragma unroll
      for (int j = 0; j < 4; ++j)
        acc[i][j] = __builtin_amdgcn_mfma_f32_16x16x32_bf16(af[i], bfr[j], acc[i][j], 0, 0, 0);
    __syncthreads();
    buf ^= 1;
  }

#pragma unroll
  for (int j = 0; j < 4; ++j) {
    const int col = bn + wn + j * 16 + l15;
    const float bv = bias[col];
#pragma unroll
    for (int i = 0; i < 4; ++i) {
#pragma unroll
      for (int q = 0; q < 4; ++q) {
        const int row = bm + wm + i * 16 + kb * 4 + q;
        float v = acc[i][j][q] + bv;
        if (RELU) v = fmaxf(v, 0.f);
        if (OBF16) ((unsigned short*)Cout)[(size_t)row * N + col] = f2bf(v);
        else       ((float*)Cout)[(size_t)row * N + col] = v;
      }
    }
  }
}

// =====================================================================
// Transforms (unchanged)
// =====================================================================
__global__ __launch_bounds__(256) void convert_bf16(const float* __restrict__ in,
                                                    unsigned short* __restrict__ out,
                                                    int n4) {
  const int i = blockIdx.x * 256 + threadIdx.x;
  if (i >= n4) return;
  float4 v = ((const float4*)in)[i];
  ushort4 o;
  o.x = f2bf(v.x); o.y = f2bf(v.y); o.z = f2bf(v.z); o.w = f2bf(v.w);
  ((ushort4*)out)[i] = o;
}

__global__ __launch_bounds__(256) void convert_f16(const float* __restrict__ in,
                                                   __half2* __restrict__ out, int n4) {
  const int i = blockIdx.x * 256 + threadIdx.x;
  if (i >= n4) return;
  float4 v = ((const float4*)in)[i];
  out[i * 2]     = __floats2half2_rn(v.x, v.y);
  out[i * 2 + 1] = __floats2half2_rn(v.z, v.w);
}

__global__ __launch_bounds__(256) void transpose_w1(const float* __restrict__ W,
                                                    unsigned short* __restrict__ Wt) {
  __shared__ float tile[32][33];
  const int n0 = blockIdx.x * 32, k0 = blockIdx.y * 32;
  const int r = threadIdx.x >> 3, c = (threadIdx.x & 7) * 4;
  float4 v = *(const float4*)(W + (size_t)(k0 + r) * PROJ + n0 + c);
  tile[r][c] = v.x; tile[r][c + 1] = v.y; tile[r][c + 2] = v.z; tile[r][c + 3] = v.w;
  __syncthreads();
  ushort4 o;
  o.x = f2bf(tile[c + 0][r]); o.y = f2bf(tile[c + 1][r]);
  o.z = f2bf(tile[c + 2][r]); o.w = f2bf(tile[c + 3][r]);
  *(ushort4*)(Wt + (size_t)(n0 + r) * INDIM + k0 + c) = o;
}

__global__ __launch_bounds__(256) void convw_prep(const float* __restrict__ W,
                                                  unsigned short* __restrict__ Wb) {
  const int id = blockIdx.x * 256 + threadIdx.x;
  const float* s = W + (size_t)id * 9;
  unsigned int v[9];
#pragma unroll
  for (int j = 0; j < 9; ++j) v[j] = f2bf(s[j]);
  uint2* d = (uint2*)(Wb + (size_t)id * 12);
  d[0] = make_uint2(v[0] | (v[1] << 16), v[2] | (v[3] << 16));
  d[1] = make_uint2(v[4] | (v[5] << 16), v[6] | (v[7] << 16));
  d[2] = make_uint2(v[8], 0u);
}

__global__ __launch_bounds__(256) void im2col(const unsigned short* __restrict__ H,
                                              unsigned short* __restrict__ Bm, int b0) {
  __shared__ unsigned int rowbuf[1536];
  const int b = b0 + blockIdx.x;
  const int t = threadIdx.x;  // = ic
  unsigned int hu[18];
  const uint2* src = (const uint2*)(H + (size_t)b * PROJ + t * 36);
#pragma unroll
  for (int j = 0; j < 9; ++j) { uint2 q = src[j]; hu[2 * j] = q.x; hu[2 * j + 1] = q.y; }
#pragma unroll
  for (int p = 0; p < 16; ++p) {
    const int pi = p >> 2, pj = p & 3;
    unsigned int v[9];
#pragma unroll
    for (int r = 0; r < 9; ++r) {
      const int j = (pi + r / 3) * 6 + pj + (r % 3);
      v[r] = (hu[j >> 1] >> ((j & 1) * 16)) & 0xffffu;
    }
    if (p) __syncthreads();
    rowbuf[t * 6 + 0] = v[0] | (v[1] << 16);
    rowbuf[t * 6 + 1] = v[2] | (v[3] << 16);
    rowbuf[t * 6 + 2] = v[4] | (v[5] << 16);
    rowbuf[t * 6 + 3] = v[6] | (v[7] << 16);
    rowbuf[t * 6 + 4] = v[8];
    rowbuf[t * 6 + 5] = 0u;
    __syncthreads();
    uint2* dst = (uint2*)(Bm + ((size_t)blockIdx.x * 16 + p) * KPAD);
    const uint2* rb = (const uint2*)rowbuf;
#pragma unroll
    for (int j = 0; j < 3; ++j) dst[t + j * 256] = rb[t + j * 256];
  }
}

__global__ __launch_bounds__(256) void squash_u(const float* __restrict__ cv,
                                                __half2* __restrict__ U) {
  const int b = blockIdx.x;
  const int t = threadIdx.x;
#pragma unroll
  for (int h = 0; h < 2; ++h) {
    const int id = t + h * 256;
    const int cap = id & 31, p = id >> 5;
    const float* s = cv + ((size_t)b * 16 + p) * 256 + cap * 8;
    float4 a = *(const float4*)s;
    float4 c = *(const float4*)(s + 4);
    float sq = a.x * a.x + a.y * a.y + a.z * a.z + a.w * a.w +
               c.x * c.x + c.y * c.y + c.z * c.z + c.w * c.w;
    const float scale = sq / (1.f + sq) / sqrtf(sq + 1e-8f);
    __half2* d = U + ((size_t)b * 4096 + cap * 128 + p * 8) / 2;
    d[0] = __floats2half2_rn(a.x * scale, a.y * scale);
    d[1] = __floats2half2_rn(a.z * scale, a.w * scale);
    d[2] = __floats2half2_rn(c.x * scale, c.y * scale);
    d[3] = __floats2half2_rn(c.z * scale, c.w * scale);
  }
}

// =====================================================================
// uhat_gemm: per capsule n, u_hat[b, n, :80] = u[b,n,:8] @ Wr[n]^T via
// MFMA f16 (K=8 zero-padded to 32). Also accumulates s0-quarter partials
// s0q[q][b][80] = sum over n in quarter q of u_hat (iter-0 has c=0.2).
// grid (CB/16, 4); 256 threads = 4 waves, each wave 32 n's.
// =====================================================================
__global__ __launch_bounds__(256) void uhat_gemm(
    const unsigned short* __restrict__ U,    // [1024][512][8] fp16
    const unsigned short* __restrict__ Wrh,  // [512][80][8] fp16
    unsigned short* __restrict__ uhat,       // [CB][512][80] fp16
    float* __restrict__ s0q,                 // [4][CB][80]
    int b0, int CB) {
  __shared__ float sred[4][16][80];  // 20 KB
  const int mt = blockIdx.x, q = blockIdx.y;
  const int t = threadIdx.x, wid = t >> 6, lane = t & 63;
  const int l15 = lane & 15, kb = lane >> 4;
  const int bm = mt * 16;       // chunk-local b base
  const int gb = b0 + bm;       // global b base

  f32x4 sacc[5];
#pragma unroll
  for (int j = 0; j < 5; ++j)
#pragma unroll
    for (int r = 0; r < 4; ++r) sacc[j][r] = 0.f;

  const uint4 zz = make_uint4(0, 0, 0, 0);
  for (int i = 0; i < 32; ++i) {
    const int n = q * 128 + wid * 32 + i;
    uint4 av = zz;
    if (kb == 0) av = *(const uint4*)(U + (size_t)(gb + l15) * 4096 + n * 8);
    const f16x8 af = __builtin_bit_cast(f16x8, av);
    f32x4 cfr[5];
#pragma unroll
    for (int jn = 0; jn < 5; ++jn) {
      uint4 bv = zz;
      if (kb == 0) bv = *(const uint4*)(Wrh + (size_t)n * 640 + (jn * 16 + l15) * 8);
      f32x4 z;
      z[0] = 0.f; z[1] = 0.f; z[2] = 0.f; z[3] = 0.f;
      cfr[jn] = __builtin_amdgcn_mfma_f32_16x16x32_f16(af, __builtin_bit_cast(f16x8, bv), z, 0, 0, 0);
    }
#pragma unroll
    for (int jn = 0; jn < 5; ++jn) {
#pragma unroll
      for (int qq = 0; qq < 4; ++qq) {
        const int row = kb * 4 + qq;
        uhat[(size_t)(bm + row) * 40960 + n * 80 + jn * 16 + l15] =
            __builtin_bit_cast(unsigned short, (_Float16)cfr[jn][qq]);
        sacc[jn][qq] += cfr[jn][qq];
      }
    }
  }
  // combine 4 waves' s0 partials
#pragma unroll
  for (int jn = 0; jn < 5; ++jn)
#pragma unroll
    for (int qq = 0; qq < 4; ++qq)
      sred[wid][kb * 4 + qq][jn * 16 + l15] = sacc[jn][qq];
  __syncthreads();
#pragma unroll
  for (int k = 0; k < 5; ++k) {
    const int id = t + k * 256;
    const int r = id / 80, col = id % 80;
    const float val = sred[0][r][col] + sred[1][r][col] + sred[2][r][col] + sred[3][r][col];
    s0q[((size_t)q * CB + bm + r) * 80 + col] = val;
  }
}

// =====================================================================
// route_pass<MODE>: one streaming pass of dynamic routing over u_hat.
// MODE 1: vprev = squash(0.2*sum s0q) = v0; computes v1; writes vsum=v0+v1.
// MODE 2: vprev = vsum (since blog2 = u_hat.(v0+v1) by linearity);
//         computes final v2; writes class_probs + v outputs.
// 256 threads; thread pair (p = t>>1, h = t&1) owns capsule n per chunk,
// h-half of d. u_hat rows read straight global->reg (L3-resident).
// =====================================================================
template <int MODE>
__global__ __launch_bounds__(256) void route_pass(
    const unsigned short* __restrict__ uhat,  // [CB][512][80] fp16
    const float* __restrict__ s0q,            // [4][CB][80] (MODE 1)
    const float* __restrict__ vsum_in,        // [CB][80] (MODE 2)
    float* __restrict__ vsum_out,             // [CB][80] (MODE 1)
    float* __restrict__ out,                  // final outputs (MODE 2)
    int b0, int CB) {
  __shared__ unsigned int vph2[40];   // v_prev as half2
  __shared__ float red[4][2][40];
  const int bl = blockIdx.x;
  const int b  = b0 + bl;
  const int t  = threadIdx.x;

  // ---- build v_prev ----
  float v0r = 0.f;
  if (t < 80) {
    if (MODE == 1) {
      float s = 0.2f * (s0q[(size_t)bl * 80 + t] +
                        s0q[((size_t)CB + bl) * 80 + t] +
                        s0q[((size_t)2 * CB + bl) * 80 + t] +
                        s0q[((size_t)3 * CB + bl) * 80 + t]);
      float sq = s * s;
      sq += __shfl_xor(sq, 1);
      sq += __shfl_xor(sq, 2);
      sq += __shfl_xor(sq, 4);
      sq += __shfl_xor(sq, 8);
      const float scale = sq / (1.f + sq) / sqrtf(sq + 1e-8f);
      v0r = s * scale;
    } else {
      v0r = vsum_in[(size_t)bl * 80 + t];
    }
    const float vnext = __shfl_down(v0r, 1);
    if ((t & 1) == 0)
      vph2[t >> 1] = __builtin_bit_cast(unsigned int, __floats2half2_rn(v0r, vnext));
  }
  __syncthreads();

  // ---- main: 4 capsules per thread-pair ----
  const int p = t >> 1, h = t & 1;
  float acc[5][8];
#pragma unroll
  for (int o = 0; o < 5; ++o)
#pragma unroll
    for (int j = 0; j < 8; ++j) acc[o][j] = 0.f;

  const unsigned short* ub = uhat + (size_t)bl * 40960;
  for (int c4 = 0; c4 < 4; ++c4) {
    const int n = c4 * 128 + p;
    const unsigned short* row = ub + n * 80 + h * 8;
    uint4 uv[5];
#pragma unroll
    for (int o = 0; o < 5; ++o) uv[o] = *(const uint4*)(row + o * 16);
    float ap[5];
#pragma unroll
    for (int o = 0; o < 5; ++o) {
      const int vb = o * 8 + h * 4;
      float a = fdot2(u2h2(uv[o].x), u2h2(vph2[vb]), 0.f);
      a = fdot2(u2h2(uv[o].y), u2h2(vph2[vb + 1]), a);
      a = fdot2(u2h2(uv[o].z), u2h2(vph2[vb + 2]), a);
      a = fdot2(u2h2(uv[o].w), u2h2(vph2[vb + 3]), a);
      ap[o] = a + __shfl_xor(a, 1);  // combine the two d-halves
    }
    float m = ap[0];
#pragma unroll
    for (int o = 1; o < 5; ++o) m = fmaxf(m, ap[o]);
    float es = 0.f, e[5];
#pragma unroll
    for (int o = 0; o < 5; ++o) { e[o] = __expf(ap[o] - m); es += e[o]; }
    const float inv = 1.f / es;
#pragma unroll
    for (int o = 0; o < 5; ++o) {
      const float cc = e[o] * inv;
      h2 hx = u2h2(uv[o].x), hy = u2h2(uv[o].y), hz = u2h2(uv[o].z), hw = u2h2(uv[o].w);
      acc[o][0] += cc * (float)hx[0]; acc[o][1] += cc * (float)hx[1];
      acc[o][2] += cc * (float)hy[0]; acc[o][3] += cc * (float)hy[1];
      acc[o][4] += cc * (float)hz[0]; acc[o][5] += cc * (float)hz[1];
      acc[o][6] += cc * (float)hw[0]; acc[o][7] += cc * (float)hw[1];
    }
  }

  // ---- reduce across same-parity lanes of each wave ----
#pragma unroll
  for (int off = 2; off <= 32; off <<= 1)
#pragma unroll
    for (int o = 0; o < 5; ++o)
#pragma unroll
      for (int j = 0; j < 8; ++j) acc[o][j] += __shfl_xor(acc[o][j], off);
  const int wid = t >> 6, lane = t & 63;
  if (lane < 2) {
#pragma unroll
    for (int o = 0; o < 5; ++o)
#pragma unroll
      for (int j = 0; j < 8; ++j) red[wid][lane][o * 8 + j] = acc[o][j];
  }
  __syncthreads();

  // ---- combine 4 waves, squash, emit ----
  if (t < 80) {
    const int o = t >> 4, d = t & 15, hh = d >> 3, dl = d & 7;
    const int c = o * 8 + dl;
    float s = red[0][hh][c] + red[1][hh][c] + red[2][hh][c] + red[3][hh][c];
    float sq = s * s;
    sq += __shfl_xor(sq, 1);
    sq += __shfl_xor(sq, 2);
    sq += __shfl_xor(sq, 4);
    sq += __shfl_xor(sq, 8);
    const float scale = sq / (1.f + sq) / sqrtf(sq + 1e-8f);
    const float vn = s * scale;
    if (MODE == 1) {
      vsum_out[(size_t)bl * 80 + t] = v0r + vn;
    } else {
      out[5 * BSZ + (size_t)b * 80 + t] = vn;
      float vv = vn * vn;
      vv += __shfl_xor(vv, 1);
      vv += __shfl_xor(vv, 2);
      vv += __shfl_xor(vv, 4);
      vv += __shfl_xor(vv, 8);
      if ((t & 15) == 0) out[(size_t)b * 5 + o] = sqrtf(vv);
    }
  }
}

// =====================================================================
extern "C" void kernel_launch(void* const* d_in, const int* in_sizes, int n_in,
                              void* d_out, int out_size, void* d_ws, size_t ws_size,
                              hipStream_t stream) {
  const float* x     = (const float*)d_in[0];
  const float* W1    = (const float*)d_in[1];
  const float* b1    = (const float*)d_in[2];
  const float* convW = (const float*)d_in[3];
  const float* convB = (const float*)d_in[4];
  const float* Wr    = (const float*)d_in[5];
  float* out = (float*)d_out;

  char* base = (char*)d_ws;
  size_t off = 0;
  auto alloc = [&](size_t bytes) { size_t o = off; off = (off + bytes + 255) & ~(size_t)255; return o; };
  // persistent (live across routing phase)
  const size_t o_wrh  = alloc((size_t)NCAP * 640 * 2);       // 0.66 MB fp16
  const size_t o_u    = alloc((size_t)BSZ * 4096 * 2);       // 8.4 MB fp16
  const size_t o_s0q  = alloc((size_t)4 * BSZ * 80 * 4);     // 1.31 MB f32
  const size_t o_vsum = alloc((size_t)BSZ * 80 * 4);         // 0.33 MB f32
  // pool: phase 1-2 buffers, later reused for u_hat
  const size_t o_pool = off;
  size_t poff = o_pool;
  auto palloc = [&](size_t bytes) { size_t o = poff; poff = (poff + bytes + 255) & ~(size_t)255; return o; };
  const size_t o_h   = palloc((size_t)BSZ * PROJ * 2);       // 18.9 MB bf16
  const size_t o_w1t = palloc((size_t)PROJ * INDIM * 2);     // 14.2 MB bf16
  const size_t o_xb  = palloc((size_t)BSZ * INDIM * 2);      // 1.6 MB bf16
  const size_t o_wb  = palloc((size_t)256 * KPAD * 2);       // 1.6 MB bf16
  const size_t o_cv  = palloc((size_t)BSZ * 16 * 256 * 4);   // 16.8 MB f32
  const size_t o_bm  = poff;                                 // chunked im2col buffer

  int chunkB = 1024;
  while (chunkB > 8 && o_bm + (size_t)chunkB * 16 * KPAD * 2 > ws_size) chunkB >>= 1;

  unsigned short* h    = (unsigned short*)(base + o_h);
  unsigned short* w1t  = (unsigned short*)(base + o_w1t);
  unsigned short* xb   = (unsigned short*)(base + o_xb);
  unsigned short* wb   = (unsigned short*)(base + o_wb);
  unsigned short* wrh  = (unsigned short*)(base + o_wrh);
  float*          cv   = (float*)(base + o_cv);
  __half2*        u    = (__half2*)(base + o_u);
  unsigned short* bm   = (unsigned short*)(base + o_bm);
  float*          s0q  = (float*)(base + o_s0q);
  float*          vsum = (float*)(base + o_vsum);
  unsigned short* uhat = (unsigned short*)(base + o_pool);   // aliases dead phase-1/2 buffers

  convert_bf16<<<(BSZ * INDIM / 4 + 255) / 256, 256, 0, stream>>>(x, xb, BSZ * INDIM / 4);
  transpose_w1<<<dim3(PROJ / 32, INDIM / 32), 256, 0, stream>>>(W1, w1t);
  convw_prep<<<256, 256, 0, stream>>>(convW, wb);
  convert_f16<<<(NCAP * 640 / 4 + 255) / 256, 256, 0, stream>>>(Wr, (__half2*)wrh, NCAP * 640 / 4);

  mfma_gemm<1, 1><<<dim3(PROJ / 128, BSZ / 128), 256, 0, stream>>>(
      xb, w1t, b1, (void*)h, BSZ, PROJ, INDIM);

  for (int b0 = 0; b0 < BSZ; b0 += chunkB) {
    im2col<<<chunkB, 256, 0, stream>>>(h, bm, b0);
    mfma_gemm<0, 0><<<dim3(2, chunkB * 16 / 128), 256, 0, stream>>>(
        bm, wb, convB, (void*)(cv + (size_t)b0 * 16 * 256), chunkB * 16, 256, KPAD);
  }

  squash_u<<<BSZ, 256, 0, stream>>>(cv, u);

  // routing: u_hat chunked over b to fit the pool
  const size_t pool_sz = ws_size > o_pool ? ws_size - o_pool : 0;
  int CB = 1024;
  while (CB > 16 && (size_t)CB * 512 * 80 * 2 > pool_sz) CB >>= 1;
  for (int b0 = 0; b0 < BSZ; b0 += CB) {
    uhat_gemm<<<dim3(CB / 16, 4), 256, 0, stream>>>(
        (const unsigned short*)u, wrh, uhat, s0q, b0, CB);
    route_pass<1><<<CB, 256, 0, stream>>>(uhat, s0q, nullptr, vsum, out, b0, CB);
    route_pass<2><<<CB, 256, 0, stream>>>(uhat, nullptr, vsum, nullptr, out, b0, CB);
  }
}

// Round 6
// 181.737 us; speedup vs baseline: 6.0648x; 1.1982x over previous
//
#include <hip/hip_runtime.h>
#include <hip/hip_fp16.h>

#define BSZ   1024
#define INDIM 768
#define PROJ  9216     // 256*6*6
#define NCAP  512
#define NCLS  5
#define K2    2304     // conv GEMM K = 9 taps * 256 ic

typedef __bf16    bf16x8 __attribute__((ext_vector_type(8)));
typedef _Float16  f16x8  __attribute__((ext_vector_type(8)));
typedef float     f32x4  __attribute__((ext_vector_type(4)));
typedef _Float16  h2     __attribute__((ext_vector_type(2)));

static __device__ __forceinline__ unsigned short f2bf(float f) {
  unsigned int x = __float_as_uint(f);
  return (unsigned short)((x + 0x7fffu + ((x >> 16) & 1u)) >> 16);
}
static __device__ __forceinline__ float bf2f(unsigned int u) {
  return __uint_as_float(u << 16);
}

#if defined(__has_builtin)
#if __has_builtin(__builtin_amdgcn_fdot2)
#define HAVE_FDOT2 1
#endif
#endif
static __device__ __forceinline__ float fdot2(h2 a, h2 b, float c) {
#ifdef HAVE_FDOT2
  return __builtin_amdgcn_fdot2(a, b, c, false);
#else
  return c + (float)a[0] * (float)b[0] + (float)a[1] * (float)b[1];
#endif
}
static __device__ __forceinline__ h2 u2h2(unsigned int u) {
  return __builtin_bit_cast(h2, u);
}

// global -> LDS direct (16B per lane)
static __device__ __forceinline__ void gload16(const void* g, void* l) {
  auto gp = reinterpret_cast<const unsigned int __attribute__((address_space(1)))*>(
      (unsigned long long)g);
  auto lp = reinterpret_cast<unsigned int __attribute__((address_space(3)))*>(
      (unsigned long long)l);
  __builtin_amdgcn_global_load_lds(gp, lp, 16, 0, 0);
}

// =====================================================================
// Unified bf16 MFMA GEMM (unchanged — passing)
// =====================================================================
template <int RELU, int OBF16>
__global__ __launch_bounds__(256) void mfma_gemm(
    const unsigned short* __restrict__ A,   // [M][K] bf16
    const unsigned short* __restrict__ Bt,  // [N][K] bf16
    const float* __restrict__ bias,         // [N]
    void* __restrict__ Cout,                // [M][N] f32 or bf16
    int M, int N, int K) {
  __shared__ __align__(16) unsigned short smem[16384];
  const int t    = threadIdx.x;
  const int bn   = blockIdx.x * 128;
  const int bm   = blockIdx.y * 128;
  const int lane = t & 63;
  const int wid  = t >> 6;
  const int wm   = (wid >> 1) * 64;
  const int wn   = (wid & 1) * 64;
  const int l15  = lane & 15;
  const int kb   = lane >> 4;

  const int r0 = t >> 2,         kc = t & 3;
  const int r1 = (t + 256) >> 2;
  const int gk0 = ((kc ^ (r0 & 3)) << 3);
  const int gk1 = ((kc ^ (r1 & 3)) << 3);

  const unsigned short* Ar0 = A  + (size_t)(bm + r0) * K + gk0;
  const unsigned short* Ar1 = A  + (size_t)(bm + r1) * K + gk1;
  const unsigned short* Br0 = Bt + (size_t)(bn + r0) * K + gk0;
  const unsigned short* Br1 = Bt + (size_t)(bn + r1) * K + gk1;

  int aoff[4], boff[4];
#pragma unroll
  for (int i = 0; i < 4; ++i) {
    const int ra = wm + i * 16 + l15;
    aoff[i] = ra * 32 + ((kb ^ (ra & 3)) << 3);
    const int rb = wn + i * 16 + l15;
    boff[i] = 4096 + rb * 32 + ((kb ^ (rb & 3)) << 3);
  }

  f32x4 acc[4][4];
#pragma unroll
  for (int i = 0; i < 4; ++i)
#pragma unroll
    for (int j = 0; j < 4; ++j)
#pragma unroll
      for (int q = 0; q < 4; ++q) acc[i][j][q] = 0.f;

  const int nk = K >> 5;
  gload16(Ar0, &smem[t * 8]);
  gload16(Ar1, &smem[(t + 256) * 8]);
  gload16(Br0, &smem[4096 + t * 8]);
  gload16(Br1, &smem[4096 + (t + 256) * 8]);
  __syncthreads();

  int buf = 0;
  for (int ks = 0; ks < nk; ++ks) {
    if (ks + 1 < nk) {
      const int k = (ks + 1) << 5;
      const int o = (buf ^ 1) * 8192;
      gload16(Ar0 + k, &smem[o + t * 8]);
      gload16(Ar1 + k, &smem[o + (t + 256) * 8]);
      gload16(Br0 + k, &smem[o + 4096 + t * 8]);
      gload16(Br1 + k, &smem[o + 4096 + (t + 256) * 8]);
    }
    const unsigned short* base = &smem[buf * 8192];
    bf16x8 af[4], bfr[4];
#pragma unroll
    for (int i = 0; i < 4; ++i) {
      af[i]  = *(const bf16x8*)(base + aoff[i]);
      bfr[i] = *(const bf16x8*)(base + boff[i]);
    }
#pragma unroll
    for (int i = 0; i < 4; ++i)
#pragma unroll
      for (int j = 0; j < 4; ++j)
        acc[i][j] = __builtin_amdgcn_mfma_f32_16x16x32_bf16(af[i], bfr[j], acc[i][j], 0, 0, 0);
    __syncthreads();
    buf ^= 1;
  }

#pragma unroll
  for (int j = 0; j < 4; ++j) {
    const int col = bn + wn + j * 16 + l15;
    const float bv = bias[col];
#pragma unroll
    for (int i = 0; i < 4; ++i) {
#pragma unroll
      for (int q = 0; q < 4; ++q) {
        const int row = bm + wm + i * 16 + kb * 4 + q;
        float v = acc[i][j][q] + bv;
        if (RELU) v = fmaxf(v, 0.f);
        if (OBF16) ((unsigned short*)Cout)[(size_t)row * N + col] = f2bf(v);
        else       ((float*)Cout)[(size_t)row * N + col] = v;
      }
    }
  }
}

// =====================================================================
// conv_gemm: implicit-im2col GEMM.
// cv[m=b*16+p][oc] = sum_{tap,ic} ht[b][sp(p,tap)][ic] * Wt2[oc][tap*256+ic]
// ht layout [1024][36][256] bf16 -> each (row, K-step) A-slice is a
// contiguous 64B chunk => global_load_lds works. Tile 64x128, BK=32,
// 4 waves (each 64x32), grid (2, 256) = 512 blocks.
// =====================================================================
__global__ __launch_bounds__(256) void conv_gemm(
    const unsigned short* __restrict__ ht,   // [1024][36][256] bf16
    const unsigned short* __restrict__ Wt2,  // [256][2304] bf16
    const float* __restrict__ convB,         // [256]
    float* __restrict__ cv) {                // [16384][256] f32
  __shared__ __align__(16) unsigned short smem[12288];  // 2 bufs * (A 2048 + B 4096)
  const int t    = threadIdx.x;
  const int bn   = blockIdx.x * 128;
  const int bm   = blockIdx.y * 64;
  const int lane = t & 63, wid = t >> 6;
  const int l15  = lane & 15, kb = lane >> 4;

  // A staging: 256 chunks, chunk=t: row=t>>2 (0..63), seg=t&3 (16B each)
  const int ar  = t >> 2, asg = t & 3;
  const int ab  = (bm + ar) >> 4, ap = (bm + ar) & 15;
  const int spb = (ap >> 2) * 6 + (ap & 3);
  const unsigned short* abase =
      ht + (size_t)ab * PROJ + spb * 256 + ((asg ^ (ar & 3)) << 3);

  // B staging: 512 chunks, this thread stages c=t and c=t+256
  const int br0 = t >> 2, br1 = (t + 256) >> 2, bsg = t & 3;
  const unsigned short* bb0 = Wt2 + (size_t)(bn + br0) * K2 + ((bsg ^ (br0 & 3)) << 3);
  const unsigned short* bb1 = Wt2 + (size_t)(bn + br1) * K2 + ((bsg ^ (br1 & 3)) << 3);

  int aoff[4], boff[2];
#pragma unroll
  for (int i = 0; i < 4; ++i) {
    const int ra = i * 16 + l15;
    aoff[i] = ra * 32 + ((kb ^ (ra & 3)) << 3);
  }
#pragma unroll
  for (int j = 0; j < 2; ++j) {
    const int rb = wid * 32 + j * 16 + l15;
    boff[j] = 2048 + rb * 32 + ((kb ^ (rb & 3)) << 3);
  }

  f32x4 acc[4][2];
#pragma unroll
  for (int i = 0; i < 4; ++i)
#pragma unroll
    for (int j = 0; j < 2; ++j)
#pragma unroll
      for (int q = 0; q < 4; ++q) acc[i][j][q] = 0.f;

  auto stage = [&](int ks, int buf) {
    const int tap = ks >> 3;
    const int dsp = tap + 3 * (tap / 3);       // (tap/3)*6 + tap%3
    const int ic0 = (ks & 7) << 5;
    unsigned short* sb = &smem[buf * 6144];
    gload16(abase + dsp * 256 + ic0, sb + t * 8);
    gload16(bb0 + ks * 32, sb + 2048 + t * 8);
    gload16(bb1 + ks * 32, sb + 2048 + (t + 256) * 8);
  };

  stage(0, 0);
  __syncthreads();

  int buf = 0;
  for (int ks = 0; ks < 72; ++ks) {
    if (ks + 1 < 72) stage(ks + 1, buf ^ 1);
    const unsigned short* base = &smem[buf * 6144];
    bf16x8 af[4], bfr[2];
#pragma unroll
    for (int i = 0; i < 4; ++i) af[i] = *(const bf16x8*)(base + aoff[i]);
#pragma unroll
    for (int j = 0; j < 2; ++j) bfr[j] = *(const bf16x8*)(base + boff[j]);
#pragma unroll
    for (int i = 0; i < 4; ++i)
#pragma unroll
      for (int j = 0; j < 2; ++j)
        acc[i][j] = __builtin_amdgcn_mfma_f32_16x16x32_bf16(af[i], bfr[j], acc[i][j], 0, 0, 0);
    __syncthreads();
    buf ^= 1;
  }

#pragma unroll
  for (int j = 0; j < 2; ++j) {
    const int col = bn + wid * 32 + j * 16 + l15;
    const float bv = convB[col];
#pragma unroll
    for (int i = 0; i < 4; ++i)
#pragma unroll
      for (int q = 0; q < 4; ++q) {
        const int row = bm + i * 16 + kb * 4 + q;
        cv[(size_t)row * 256 + col] = acc[i][j][q] + bv;
      }
  }
}

// =====================================================================
// Transforms
// =====================================================================
__global__ __launch_bounds__(256) void convert_bf16(const float* __restrict__ in,
                                                    unsigned short* __restrict__ out,
                                                    int n4) {
  const int i = blockIdx.x * 256 + threadIdx.x;
  if (i >= n4) return;
  float4 v = ((const float4*)in)[i];
  ushort4 o;
  o.x = f2bf(v.x); o.y = f2bf(v.y); o.z = f2bf(v.z); o.w = f2bf(v.w);
  ((ushort4*)out)[i] = o;
}

__global__ __launch_bounds__(256) void convert_f16(const float* __restrict__ in,
                                                   __half2* __restrict__ out, int n4) {
  const int i = blockIdx.x * 256 + threadIdx.x;
  if (i >= n4) return;
  float4 v = ((const float4*)in)[i];
  out[i * 2]     = __floats2half2_rn(v.x, v.y);
  out[i * 2 + 1] = __floats2half2_rn(v.z, v.w);
}

// W1 [768][9216] f32 -> W1tp[perm(n)][k] bf16, perm(n) = (n%36)*256 + n/36.
// So GEMM1's output column n' = sp*256 + c, i.e. h in [b][sp][c] layout.
__global__ __launch_bounds__(256) void transpose_w1_perm(const float* __restrict__ W,
                                                         unsigned short* __restrict__ Wt) {
  __shared__ float tile[32][33];
  const int n0 = blockIdx.x * 32, k0 = blockIdx.y * 32;
  const int r = threadIdx.x >> 3, c = (threadIdx.x & 7) * 4;
  float4 v = *(const float4*)(W + (size_t)(k0 + r) * PROJ + n0 + c);
  tile[r][c] = v.x; tile[r][c + 1] = v.y; tile[r][c + 2] = v.z; tile[r][c + 3] = v.w;
  __syncthreads();
  ushort4 o;
  o.x = f2bf(tile[c + 0][r]); o.y = f2bf(tile[c + 1][r]);
  o.z = f2bf(tile[c + 2][r]); o.w = f2bf(tile[c + 3][r]);
  const int nn = n0 + r;
  const int prow = (nn % 36) * 256 + nn / 36;
  *(ushort4*)(Wt + (size_t)prow * INDIM + k0 + c) = o;
}

__global__ __launch_bounds__(256) void perm_bias(const float* __restrict__ b1,
                                                 float* __restrict__ pb1) {
  const int n = blockIdx.x * 256 + threadIdx.x;
  if (n >= PROJ) return;
  pb1[(n % 36) * 256 + n / 36] = b1[n];
}

// convW [oc][ic][9] f32 -> Wt2[oc][tap*256+ic] bf16
__global__ __launch_bounds__(256) void convw_prep2(const float* __restrict__ W,
                                                   unsigned short* __restrict__ Wt2) {
  const int id = blockIdx.x * 256 + threadIdx.x;  // oc*256 + ic
  const int oc = id >> 8, ic = id & 255;
  const float* s = W + (size_t)id * 9;
#pragma unroll
  for (int tap = 0; tap < 9; ++tap)
    Wt2[(size_t)oc * K2 + tap * 256 + ic] = f2bf(s[tap]);
}

__global__ __launch_bounds__(256) void squash_u(const float* __restrict__ cv,
                                                __half2* __restrict__ U) {
  const int b = blockIdx.x;
  const int t = threadIdx.x;
#pragma unroll
  for (int h = 0; h < 2; ++h) {
    const int id = t + h * 256;
    const int cap = id & 31, p = id >> 5;
    const float* s = cv + ((size_t)b * 16 + p) * 256 + cap * 8;
    float4 a = *(const float4*)s;
    float4 c = *(const float4*)(s + 4);
    float sq = a.x * a.x + a.y * a.y + a.z * a.z + a.w * a.w +
               c.x * c.x + c.y * c.y + c.z * c.z + c.w * c.w;
    const float scale = sq / (1.f + sq) / sqrtf(sq + 1e-8f);
    __half2* d = U + ((size_t)b * 4096 + cap * 128 + p * 8) / 2;
    d[0] = __floats2half2_rn(a.x * scale, a.y * scale);
    d[1] = __floats2half2_rn(a.z * scale, a.w * scale);
    d[2] = __floats2half2_rn(c.x * scale, c.y * scale);
    d[3] = __floats2half2_rn(c.z * scale, c.w * scale);
  }
}

// =====================================================================
// uhat_gemm + route_pass (unchanged — passing)
// =====================================================================
__global__ __launch_bounds__(256) void uhat_gemm(
    const unsigned short* __restrict__ U,    // [1024][512][8] fp16
    const unsigned short* __restrict__ Wrh,  // [512][80][8] fp16
    unsigned short* __restrict__ uhat,       // [CB][512][80] fp16
    float* __restrict__ s0q,                 // [4][CB][80]
    int b0, int CB) {
  __shared__ float sred[4][16][80];
  const int mt = blockIdx.x, q = blockIdx.y;
  const int t = threadIdx.x, wid = t >> 6, lane = t & 63;
  const int l15 = lane & 15, kb = lane >> 4;
  const int bm = mt * 16;
  const int gb = b0 + bm;

  f32x4 sacc[5];
#pragma unroll
  for (int j = 0; j < 5; ++j)
#pragma unroll
    for (int r = 0; r < 4; ++r) sacc[j][r] = 0.f;

  const uint4 zz = make_uint4(0, 0, 0, 0);
  for (int i = 0; i < 32; ++i) {
    const int n = q * 128 + wid * 32 + i;
    uint4 av = zz;
    if (kb == 0) av = *(const uint4*)(U + (size_t)(gb + l15) * 4096 + n * 8);
    const f16x8 af = __builtin_bit_cast(f16x8, av);
    f32x4 cfr[5];
#pragma unroll
    for (int jn = 0; jn < 5; ++jn) {
      uint4 bv = zz;
      if (kb == 0) bv = *(const uint4*)(Wrh + (size_t)n * 640 + (jn * 16 + l15) * 8);
      f32x4 z;
      z[0] = 0.f; z[1] = 0.f; z[2] = 0.f; z[3] = 0.f;
      cfr[jn] = __builtin_amdgcn_mfma_f32_16x16x32_f16(af, __builtin_bit_cast(f16x8, bv), z, 0, 0, 0);
    }
#pragma unroll
    for (int jn = 0; jn < 5; ++jn) {
#pragma unroll
      for (int qq = 0; qq < 4; ++qq) {
        const int row = kb * 4 + qq;
        uhat[(size_t)(bm + row) * 40960 + n * 80 + jn * 16 + l15] =
            __builtin_bit_cast(unsigned short, (_Float16)cfr[jn][qq]);
        sacc[jn][qq] += cfr[jn][qq];
      }
    }
  }
#pragma unroll
  for (int jn = 0; jn < 5; ++jn)
#pragma unroll
    for (int qq = 0; qq < 4; ++qq)
      sred[wid][kb * 4 + qq][jn * 16 + l15] = sacc[jn][qq];
  __syncthreads();
#pragma unroll
  for (int k = 0; k < 5; ++k) {
    const int id = t + k * 256;
    const int r = id / 80, col = id % 80;
    const float val = sred[0][r][col] + sred[1][r][col] + sred[2][r][col] + sred[3][r][col];
    s0q[((size_t)q * CB + bm + r) * 80 + col] = val;
  }
}

template <int MODE>
__global__ __launch_bounds__(256) void route_pass(
    const unsigned short* __restrict__ uhat,  // [CB][512][80] fp16
    const float* __restrict__ s0q,            // [4][CB][80] (MODE 1)
    const float* __restrict__ vsum_in,        // [CB][80] (MODE 2)
    float* __restrict__ vsum_out,             // [CB][80] (MODE 1)
    float* __restrict__ out,                  // final outputs (MODE 2)
    int b0, int CB) {
  __shared__ unsigned int vph2[40];
  __shared__ float red[4][2][40];
  const int bl = blockIdx.x;
  const int b  = b0 + bl;
  const int t  = threadIdx.x;

  float v0r = 0.f;
  if (t < 80) {
    if (MODE == 1) {
      float s = 0.2f * (s0q[(size_t)bl * 80 + t] +
                        s0q[((size_t)CB + bl) * 80 + t] +
                        s0q[((size_t)2 * CB + bl) * 80 + t] +
                        s0q[((size_t)3 * CB + bl) * 80 + t]);
      float sq = s * s;
      sq += __shfl_xor(sq, 1);
      sq += __shfl_xor(sq, 2);
      sq += __shfl_xor(sq, 4);
      sq += __shfl_xor(sq, 8);
      const float scale = sq / (1.f + sq) / sqrtf(sq + 1e-8f);
      v0r = s * scale;
    } else {
      v0r = vsum_in[(size_t)bl * 80 + t];
    }
    const float vnext = __shfl_down(v0r, 1);
    if ((t & 1) == 0)
      vph2[t >> 1] = __builtin_bit_cast(unsigned int, __floats2half2_rn(v0r, vnext));
  }
  __syncthreads();

  const int p = t >> 1, h = t & 1;
  float acc[5][8];
#pragma unroll
  for (int o = 0; o < 5; ++o)
#pragma unroll
    for (int j = 0; j < 8; ++j) acc[o][j] = 0.f;

  const unsigned short* ub = uhat + (size_t)bl * 40960;
  for (int c4 = 0; c4 < 4; ++c4) {
    const int n = c4 * 128 + p;
    const unsigned short* row = ub + n * 80 + h * 8;
    uint4 uv[5];
#pragma unroll
    for (int o = 0; o < 5; ++o) uv[o] = *(const uint4*)(row + o * 16);
    float ap[5];
#pragma unroll
    for (int o = 0; o < 5; ++o) {
      const int vb = o * 8 + h * 4;
      float a = fdot2(u2h2(uv[o].x), u2h2(vph2[vb]), 0.f);
      a = fdot2(u2h2(uv[o].y), u2h2(vph2[vb + 1]), a);
      a = fdot2(u2h2(uv[o].z), u2h2(vph2[vb + 2]), a);
      a = fdot2(u2h2(uv[o].w), u2h2(vph2[vb + 3]), a);
      ap[o] = a + __shfl_xor(a, 1);
    }
    float m = ap[0];
#pragma unroll
    for (int o = 1; o < 5; ++o) m = fmaxf(m, ap[o]);
    float es = 0.f, e[5];
#pragma unroll
    for (int o = 0; o < 5; ++o) { e[o] = __expf(ap[o] - m); es += e[o]; }
    const float inv = 1.f / es;
#pragma unroll
    for (int o = 0; o < 5; ++o) {
      const float cc = e[o] * inv;
      h2 hx = u2h2(uv[o].x), hy = u2h2(uv[o].y), hz = u2h2(uv[o].z), hw = u2h2(uv[o].w);
      acc[o][0] += cc * (float)hx[0]; acc[o][1] += cc * (float)hx[1];
      acc[o][2] += cc * (float)hy[0]; acc[o][3] += cc * (float)hy[1];
      acc[o][4] += cc * (float)hz[0]; acc[o][5] += cc * (float)hz[1];
      acc[o][6] += cc * (float)hw[0]; acc[o][7] += cc * (float)hw[1];
    }
  }

#pragma unroll
  for (int off = 2; off <= 32; off <<= 1)
#pragma unroll
    for (int o = 0; o < 5; ++o)
#pragma unroll
      for (int j = 0; j < 8; ++j) acc[o][j] += __shfl_xor(acc[o][j], off);
  const int wid = t >> 6, lane = t & 63;
  if (lane < 2) {
#pragma unroll
    for (int o = 0; o < 5; ++o)
#pragma unroll
      for (int j = 0; j < 8; ++j) red[wid][lane][o * 8 + j] = acc[o][j];
  }
  __syncthreads();

  if (t < 80) {
    const int o = t >> 4, d = t & 15, hh = d >> 3, dl = d & 7;
    const int c = o * 8 + dl;
    float s = red[0][hh][c] + red[1][hh][c] + red[2][hh][c] + red[3][hh][c];
    float sq = s * s;
    sq += __shfl_xor(sq, 1);
    sq += __shfl_xor(sq, 2);
    sq += __shfl_xor(sq, 4);
    sq += __shfl_xor(sq, 8);
    const float scale = sq / (1.f + sq) / sqrtf(sq + 1e-8f);
    const float vn = s * scale;
    if (MODE == 1) {
      vsum_out[(size_t)bl * 80 + t] = v0r + vn;
    } else {
      out[5 * BSZ + (size_t)b * 80 + t] = vn;
      float vv = vn * vn;
      vv += __shfl_xor(vv, 1);
      vv += __shfl_xor(vv, 2);
      vv += __shfl_xor(vv, 4);
      vv += __shfl_xor(vv, 8);
      if ((t & 15) == 0) out[(size_t)b * 5 + o] = sqrtf(vv);
    }
  }
}

// =====================================================================
extern "C" void kernel_launch(void* const* d_in, const int* in_sizes, int n_in,
                              void* d_out, int out_size, void* d_ws, size_t ws_size,
                              hipStream_t stream) {
  const float* x     = (const float*)d_in[0];
  const float* W1    = (const float*)d_in[1];
  const float* b1    = (const float*)d_in[2];
  const float* convW = (const float*)d_in[3];
  const float* convB = (const float*)d_in[4];
  const float* Wr    = (const float*)d_in[5];
  float* out = (float*)d_out;

  char* base = (char*)d_ws;
  size_t off = 0;
  auto alloc = [&](size_t bytes) { size_t o = off; off = (off + bytes + 255) & ~(size_t)255; return o; };
  // persistent (live across routing phase)
  const size_t o_wrh  = alloc((size_t)NCAP * 640 * 2);       // 0.66 MB fp16
  const size_t o_u    = alloc((size_t)BSZ * 4096 * 2);       // 8.4 MB fp16
  const size_t o_s0q  = alloc((size_t)4 * BSZ * 80 * 4);     // 1.31 MB f32
  const size_t o_vsum = alloc((size_t)BSZ * 80 * 4);         // 0.33 MB f32
  // pool: phase 1-2 buffers, later reused for u_hat
  const size_t o_pool = off;
  size_t poff = o_pool;
  auto palloc = [&](size_t bytes) { size_t o = poff; poff = (poff + bytes + 255) & ~(size_t)255; return o; };
  const size_t o_ht  = palloc((size_t)BSZ * PROJ * 2);       // 18.9 MB bf16
  const size_t o_w1t = palloc((size_t)PROJ * INDIM * 2);     // 14.2 MB bf16
  const size_t o_xb  = palloc((size_t)BSZ * INDIM * 2);      // 1.6 MB bf16
  const size_t o_wt2 = palloc((size_t)256 * K2 * 2);         // 1.2 MB bf16
  const size_t o_pb1 = palloc((size_t)PROJ * 4);             // 36 KB f32
  const size_t o_cv  = palloc((size_t)BSZ * 16 * 256 * 4);   // 16.8 MB f32

  unsigned short* ht   = (unsigned short*)(base + o_ht);
  unsigned short* w1t  = (unsigned short*)(base + o_w1t);
  unsigned short* xb   = (unsigned short*)(base + o_xb);
  unsigned short* wt2  = (unsigned short*)(base + o_wt2);
  float*          pb1  = (float*)(base + o_pb1);
  unsigned short* wrh  = (unsigned short*)(base + o_wrh);
  float*          cv   = (float*)(base + o_cv);
  __half2*        u    = (__half2*)(base + o_u);
  float*          s0q  = (float*)(base + o_s0q);
  float*          vsum = (float*)(base + o_vsum);
  unsigned short* uhat = (unsigned short*)(base + o_pool);   // aliases dead phase-1/2 buffers

  convert_bf16<<<(BSZ * INDIM / 4 + 255) / 256, 256, 0, stream>>>(x, xb, BSZ * INDIM / 4);
  transpose_w1_perm<<<dim3(PROJ / 32, INDIM / 32), 256, 0, stream>>>(W1, w1t);
  perm_bias<<<PROJ / 256, 256, 0, stream>>>(b1, pb1);
  convw_prep2<<<256, 256, 0, stream>>>(convW, wt2);
  convert_f16<<<(NCAP * 640 / 4 + 255) / 256, 256, 0, stream>>>(Wr, (__half2*)wrh, NCAP * 640 / 4);

  // ht = relu(x @ W1 + b1) in [b][sp][c] layout
  mfma_gemm<1, 1><<<dim3(PROJ / 128, BSZ / 128), 256, 0, stream>>>(
      xb, w1t, pb1, (void*)ht, BSZ, PROJ, INDIM);

  // conv as implicit-im2col GEMM (no materialized im2col buffer)
  conv_gemm<<<dim3(2, 256), 256, 0, stream>>>(ht, wt2, convB, cv);

  squash_u<<<BSZ, 256, 0, stream>>>(cv, u);

  // routing: u_hat chunked over b to fit the pool
  const size_t pool_sz = ws_size > o_pool ? ws_size - o_pool : 0;
  int CB = 1024;
  while (CB > 16 && (size_t)CB * 512 * 80 * 2 > pool_sz) CB >>= 1;
  for (int b0 = 0; b0 < BSZ; b0 += CB) {
    uhat_gemm<<<dim3(CB / 16, 4), 256, 0, stream>>>(
        (const unsigned short*)u, wrh, uhat, s0q, b0, CB);
    route_pass<1><<<CB, 256, 0, stream>>>(uhat, s0q, nullptr, vsum, out, b0, CB);
    route_pass<2><<<CB, 256, 0, stream>>>(uhat, nullptr, vsum, nullptr, out, b0, CB);
  }
}

// Round 7
// 160.298 us; speedup vs baseline: 6.8760x; 1.1337x over previous
//
#include <hip/hip_runtime.h>
#include <hip/hip_fp16.h>

#define BSZ   1024
#define INDIM 768
#define PROJ  9216     // 256*6*6
#define NCAP  512
#define NCLS  5
#define K2    2304     // conv GEMM K = 9 taps * 256 ic

typedef __bf16    bf16x8 __attribute__((ext_vector_type(8)));
typedef _Float16  f16x8  __attribute__((ext_vector_type(8)));
typedef float     f32x4  __attribute__((ext_vector_type(4)));
typedef _Float16  h2     __attribute__((ext_vector_type(2)));

static __device__ __forceinline__ unsigned short f2bf(float f) {
  unsigned int x = __float_as_uint(f);
  return (unsigned short)((x + 0x7fffu + ((x >> 16) & 1u)) >> 16);
}
static __device__ __forceinline__ float bf2f(unsigned int u) {
  return __uint_as_float(u << 16);
}

#if defined(__has_builtin)
#if __has_builtin(__builtin_amdgcn_fdot2)
#define HAVE_FDOT2 1
#endif
#endif
static __device__ __forceinline__ float fdot2(h2 a, h2 b, float c) {
#ifdef HAVE_FDOT2
  return __builtin_amdgcn_fdot2(a, b, c, false);
#else
  return c + (float)a[0] * (float)b[0] + (float)a[1] * (float)b[1];
#endif
}
static __device__ __forceinline__ h2 u2h2(unsigned int u) {
  return __builtin_bit_cast(h2, u);
}
static __device__ __forceinline__ unsigned short f2h(float f) {
  return __builtin_bit_cast(unsigned short, (_Float16)f);
}

// global -> LDS direct (16B per lane)
static __device__ __forceinline__ void gload16(const void* g, void* l) {
  auto gp = reinterpret_cast<const unsigned int __attribute__((address_space(1)))*>(
      (unsigned long long)g);
  auto lp = reinterpret_cast<unsigned int __attribute__((address_space(3)))*>(
      (unsigned long long)l);
  __builtin_amdgcn_global_load_lds(gp, lp, 16, 0, 0);
}

// =====================================================================
// Unified bf16 MFMA GEMM (unchanged — passing)
// =====================================================================
template <int RELU, int OBF16>
__global__ __launch_bounds__(256) void mfma_gemm(
    const unsigned short* __restrict__ A,   // [M][K] bf16
    const unsigned short* __restrict__ Bt,  // [N][K] bf16
    const float* __restrict__ bias,         // [N]
    void* __restrict__ Cout,                // [M][N] f32 or bf16
    int M, int N, int K) {
  __shared__ __align__(16) unsigned short smem[16384];
  const int t    = threadIdx.x;
  const int bn   = blockIdx.x * 128;
  const int bm   = blockIdx.y * 128;
  const int lane = t & 63;
  const int wid  = t >> 6;
  const int wm   = (wid >> 1) * 64;
  const int wn   = (wid & 1) * 64;
  const int l15  = lane & 15;
  const int kb   = lane >> 4;

  const int r0 = t >> 2,         kc = t & 3;
  const int r1 = (t + 256) >> 2;
  const int gk0 = ((kc ^ (r0 & 3)) << 3);
  const int gk1 = ((kc ^ (r1 & 3)) << 3);

  const unsigned short* Ar0 = A  + (size_t)(bm + r0) * K + gk0;
  const unsigned short* Ar1 = A  + (size_t)(bm + r1) * K + gk1;
  const unsigned short* Br0 = Bt + (size_t)(bn + r0) * K + gk0;
  const unsigned short* Br1 = Bt + (size_t)(bn + r1) * K + gk1;

  int aoff[4], boff[4];
#pragma unroll
  for (int i = 0; i < 4; ++i) {
    const int ra = wm + i * 16 + l15;
    aoff[i] = ra * 32 + ((kb ^ (ra & 3)) << 3);
    const int rb = wn + i * 16 + l15;
    boff[i] = 4096 + rb * 32 + ((kb ^ (rb & 3)) << 3);
  }

  f32x4 acc[4][4];
#pragma unroll
  for (int i = 0; i < 4; ++i)
#pragma unroll
    for (int j = 0; j < 4; ++j)
#pragma unroll
      for (int q = 0; q < 4; ++q) acc[i][j][q] = 0.f;

  const int nk = K >> 5;
  gload16(Ar0, &smem[t * 8]);
  gload16(Ar1, &smem[(t + 256) * 8]);
  gload16(Br0, &smem[4096 + t * 8]);
  gload16(Br1, &smem[4096 + (t + 256) * 8]);
  __syncthreads();

  int buf = 0;
  for (int ks = 0; ks < nk; ++ks) {
    if (ks + 1 < nk) {
      const int k = (ks + 1) << 5;
      const int o = (buf ^ 1) * 8192;
      gload16(Ar0 + k, &smem[o + t * 8]);
      gload16(Ar1 + k, &smem[o + (t + 256) * 8]);
      gload16(Br0 + k, &smem[o + 4096 + t * 8]);
      gload16(Br1 + k, &smem[o + 4096 + (t + 256) * 8]);
    }
    const unsigned short* base = &smem[buf * 8192];
    bf16x8 af[4], bfr[4];
#pragma unroll
    for (int i = 0; i < 4; ++i) {
      af[i]  = *(const bf16x8*)(base + aoff[i]);
      bfr[i] = *(const bf16x8*)(base + boff[i]);
    }
#pragma unroll
    for (int i = 0; i < 4; ++i)
#pragma unroll
      for (int j = 0; j < 4; ++j)
        acc[i][j] = __builtin_amdgcn_mfma_f32_16x16x32_bf16(af[i], bfr[j], acc[i][j], 0, 0, 0);
    __syncthreads();
    buf ^= 1;
  }

#pragma unroll
  for (int j = 0; j < 4; ++j) {
    const int col = bn + wn + j * 16 + l15;
    const float bv = bias[col];
#pragma unroll
    for (int i = 0; i < 4; ++i) {
#pragma unroll
      for (int q = 0; q < 4; ++q) {
        const int row = bm + wm + i * 16 + kb * 4 + q;
        float v = acc[i][j][q] + bv;
        if (RELU) v = fmaxf(v, 0.f);
        if (OBF16) ((unsigned short*)Cout)[(size_t)row * N + col] = f2bf(v);
        else       ((float*)Cout)[(size_t)row * N + col] = v;
      }
    }
  }
}

// =====================================================================
// conv_gemm: implicit-im2col GEMM, fp16 output.
// =====================================================================
__global__ __launch_bounds__(256) void conv_gemm(
    const unsigned short* __restrict__ ht,   // [1024][36][256] bf16
    const unsigned short* __restrict__ Wt2,  // [256][2304] bf16
    const float* __restrict__ convB,         // [256]
    unsigned short* __restrict__ cv) {       // [16384][256] fp16
  __shared__ __align__(16) unsigned short smem[12288];  // 2 bufs * (A 2048 + B 4096)
  const int t    = threadIdx.x;
  const int bn   = blockIdx.x * 128;
  const int bm   = blockIdx.y * 64;
  const int lane = t & 63, wid = t >> 6;
  const int l15  = lane & 15, kb = lane >> 4;

  const int ar  = t >> 2, asg = t & 3;
  const int ab  = (bm + ar) >> 4, ap = (bm + ar) & 15;
  const int spb = (ap >> 2) * 6 + (ap & 3);
  const unsigned short* abase =
      ht + (size_t)ab * PROJ + spb * 256 + ((asg ^ (ar & 3)) << 3);

  const int br0 = t >> 2, br1 = (t + 256) >> 2, bsg = t & 3;
  const unsigned short* bb0 = Wt2 + (size_t)(bn + br0) * K2 + ((bsg ^ (br0 & 3)) << 3);
  const unsigned short* bb1 = Wt2 + (size_t)(bn + br1) * K2 + ((bsg ^ (br1 & 3)) << 3);

  int aoff[4], boff[2];
#pragma unroll
  for (int i = 0; i < 4; ++i) {
    const int ra = i * 16 + l15;
    aoff[i] = ra * 32 + ((kb ^ (ra & 3)) << 3);
  }
#pragma unroll
  for (int j = 0; j < 2; ++j) {
    const int rb = wid * 32 + j * 16 + l15;
    boff[j] = 2048 + rb * 32 + ((kb ^ (rb & 3)) << 3);
  }

  f32x4 acc[4][2];
#pragma unroll
  for (int i = 0; i < 4; ++i)
#pragma unroll
    for (int j = 0; j < 2; ++j)
#pragma unroll
      for (int q = 0; q < 4; ++q) acc[i][j][q] = 0.f;

  auto stage = [&](int ks, int buf) {
    const int tap = ks >> 3;
    const int dsp = tap + 3 * (tap / 3);
    const int ic0 = (ks & 7) << 5;
    unsigned short* sb = &smem[buf * 6144];
    gload16(abase + dsp * 256 + ic0, sb + t * 8);
    gload16(bb0 + ks * 32, sb + 2048 + t * 8);
    gload16(bb1 + ks * 32, sb + 2048 + (t + 256) * 8);
  };

  stage(0, 0);
  __syncthreads();

  int buf = 0;
  for (int ks = 0; ks < 72; ++ks) {
    if (ks + 1 < 72) stage(ks + 1, buf ^ 1);
    const unsigned short* base = &smem[buf * 6144];
    bf16x8 af[4], bfr[2];
#pragma unroll
    for (int i = 0; i < 4; ++i) af[i] = *(const bf16x8*)(base + aoff[i]);
#pragma unroll
    for (int j = 0; j < 2; ++j) bfr[j] = *(const bf16x8*)(base + boff[j]);
#pragma unroll
    for (int i = 0; i < 4; ++i)
#pragma unroll
      for (int j = 0; j < 2; ++j)
        acc[i][j] = __builtin_amdgcn_mfma_f32_16x16x32_bf16(af[i], bfr[j], acc[i][j], 0, 0, 0);
    __syncthreads();
    buf ^= 1;
  }

#pragma unroll
  for (int j = 0; j < 2; ++j) {
    const int col = bn + wid * 32 + j * 16 + l15;
    const float bv = convB[col];
#pragma unroll
    for (int i = 0; i < 4; ++i)
#pragma unroll
      for (int q = 0; q < 4; ++q) {
        const int row = bm + i * 16 + kb * 4 + q;
        cv[(size_t)row * 256 + col] = f2h(acc[i][j][q] + bv);
      }
  }
}

// =====================================================================
// Transforms
// =====================================================================
__global__ __launch_bounds__(256) void convert_bf16(const float* __restrict__ in,
                                                    unsigned short* __restrict__ out,
                                                    int n4) {
  const int i = blockIdx.x * 256 + threadIdx.x;
  if (i >= n4) return;
  float4 v = ((const float4*)in)[i];
  ushort4 o;
  o.x = f2bf(v.x); o.y = f2bf(v.y); o.z = f2bf(v.z); o.w = f2bf(v.w);
  ((ushort4*)out)[i] = o;
}

__global__ __launch_bounds__(256) void convert_f16(const float* __restrict__ in,
                                                   __half2* __restrict__ out, int n4) {
  const int i = blockIdx.x * 256 + threadIdx.x;
  if (i >= n4) return;
  float4 v = ((const float4*)in)[i];
  out[i * 2]     = __floats2half2_rn(v.x, v.y);
  out[i * 2 + 1] = __floats2half2_rn(v.z, v.w);
}

__global__ __launch_bounds__(256) void transpose_w1_perm(const float* __restrict__ W,
                                                         unsigned short* __restrict__ Wt) {
  __shared__ float tile[32][33];
  const int n0 = blockIdx.x * 32, k0 = blockIdx.y * 32;
  const int r = threadIdx.x >> 3, c = (threadIdx.x & 7) * 4;
  float4 v = *(const float4*)(W + (size_t)(k0 + r) * PROJ + n0 + c);
  tile[r][c] = v.x; tile[r][c + 1] = v.y; tile[r][c + 2] = v.z; tile[r][c + 3] = v.w;
  __syncthreads();
  ushort4 o;
  o.x = f2bf(tile[c + 0][r]); o.y = f2bf(tile[c + 1][r]);
  o.z = f2bf(tile[c + 2][r]); o.w = f2bf(tile[c + 3][r]);
  const int nn = n0 + r;
  const int prow = (nn % 36) * 256 + nn / 36;
  *(ushort4*)(Wt + (size_t)prow * INDIM + k0 + c) = o;
}

__global__ __launch_bounds__(256) void perm_bias(const float* __restrict__ b1,
                                                 float* __restrict__ pb1) {
  const int n = blockIdx.x * 256 + threadIdx.x;
  if (n >= PROJ) return;
  pb1[(n % 36) * 256 + n / 36] = b1[n];
}

__global__ __launch_bounds__(256) void convw_prep2(const float* __restrict__ W,
                                                   unsigned short* __restrict__ Wt2) {
  const int id = blockIdx.x * 256 + threadIdx.x;
  const int oc = id >> 8, ic = id & 255;
  const float* s = W + (size_t)id * 9;
#pragma unroll
  for (int tap = 0; tap < 9; ++tap)
    Wt2[(size_t)oc * K2 + tap * 256 + ic] = f2bf(s[tap]);
}

__global__ __launch_bounds__(256) void squash_u(const unsigned short* __restrict__ cv,
                                                __half2* __restrict__ U) {
  const int b = blockIdx.x;
  const int t = threadIdx.x;
#pragma unroll
  for (int h = 0; h < 2; ++h) {
    const int id = t + h * 256;
    const int cap = id & 31, p = id >> 5;
    const unsigned short* s = cv + ((size_t)b * 16 + p) * 256 + cap * 8;
    uint4 qv = *(const uint4*)s;
    h2 a0 = u2h2(qv.x), a1 = u2h2(qv.y), a2 = u2h2(qv.z), a3 = u2h2(qv.w);
    float f0 = a0[0], f1 = a0[1], f2 = a1[0], f3 = a1[1];
    float f4 = a2[0], f5 = a2[1], f6 = a3[0], f7 = a3[1];
    float sq = f0 * f0 + f1 * f1 + f2 * f2 + f3 * f3 +
               f4 * f4 + f5 * f5 + f6 * f6 + f7 * f7;
    const float scale = sq / (1.f + sq) / sqrtf(sq + 1e-8f);
    __half2* d = U + ((size_t)b * 4096 + cap * 128 + p * 8) / 2;
    d[0] = __floats2half2_rn(f0 * scale, f1 * scale);
    d[1] = __floats2half2_rn(f2 * scale, f3 * scale);
    d[2] = __floats2half2_rn(f4 * scale, f5 * scale);
    d[3] = __floats2half2_rn(f6 * scale, f7 * scale);
  }
}

// =====================================================================
// uhat_gemm v2: swapped operands (A=Wr rows=od, B=u cols=b) so each
// lane's 4 acc regs are 4 consecutive od of one (b,n) row -> ushort4
// stores. 512 threads = 8 waves; grid (CB/16, 8); wave handles 8 n's.
// s0 partials: s0q[8][CB][80].
// =====================================================================
__global__ __launch_bounds__(512) void uhat_gemm(
    const unsigned short* __restrict__ U,    // [1024][512][8] fp16
    const unsigned short* __restrict__ Wrh,  // [512][80][8] fp16
    unsigned short* __restrict__ uhat,       // [CB][512][80] fp16
    float* __restrict__ s0q,                 // [8][CB][80]
    int b0, int CB) {
  __shared__ float sred[8][16][80];  // 40 KB
  const int mt = blockIdx.x, q = blockIdx.y;   // q 0..7
  const int t = threadIdx.x, wid = t >> 6, lane = t & 63;
  const int l15 = lane & 15, kb = lane >> 4;
  const int bm = mt * 16;
  const int gb = b0 + bm;

  // lane accumulates s0 for b = l15, od = jn*16 + kb*4 + qq
  f32x4 sacc[5];
#pragma unroll
  for (int j = 0; j < 5; ++j)
#pragma unroll
    for (int r = 0; r < 4; ++r) sacc[j][r] = 0.f;

  const uint4 zz = make_uint4(0, 0, 0, 0);
#pragma unroll
  for (int i = 0; i < 8; ++i) {
    const int n = q * 64 + wid * 8 + i;
    uint4 av = zz;
    if (kb == 0) av = *(const uint4*)(U + (size_t)(gb + l15) * 4096 + n * 8);
    const f16x8 uf = __builtin_bit_cast(f16x8, av);  // B-operand: col=b, k=i
#pragma unroll
    for (int jn = 0; jn < 5; ++jn) {
      uint4 wv = zz;
      if (kb == 0) wv = *(const uint4*)(Wrh + (size_t)n * 640 + (jn * 16 + l15) * 8);
      f32x4 z;
      z[0] = 0.f; z[1] = 0.f; z[2] = 0.f; z[3] = 0.f;
      // D[od_row][b_col]: row = jn*16 + kb*4 + qq, col = l15
      f32x4 c = __builtin_amdgcn_mfma_f32_16x16x32_f16(
          __builtin_bit_cast(f16x8, wv), uf, z, 0, 0, 0);
      ushort4 st;
      st.x = f2h(c[0]); st.y = f2h(c[1]); st.z = f2h(c[2]); st.w = f2h(c[3]);
      *(ushort4*)(uhat + ((size_t)(bm + l15) * 512 + n) * 80 + jn * 16 + kb * 4) = st;
#pragma unroll
      for (int qq = 0; qq < 4; ++qq) sacc[jn][qq] += c[qq];
    }
  }

  // cross-wave s0 combine
#pragma unroll
  for (int jn = 0; jn < 5; ++jn)
#pragma unroll
    for (int qq = 0; qq < 4; ++qq)
      sred[wid][l15][jn * 16 + kb * 4 + qq] = sacc[jn][qq];
  __syncthreads();
#pragma unroll
  for (int k = 0; k < 3; ++k) {
    const int id = t + k * 512;
    if (id < 1280) {
      const int bb = id / 80, od = id % 80;
      float val = 0.f;
#pragma unroll
      for (int w = 0; w < 8; ++w) val += sred[w][bb][od];
      s0q[((size_t)q * CB + bm + bb) * 80 + od] = val;
    }
  }
}

// =====================================================================
// route_pass<MODE> (MODE1 now sums 8 s0q groups; otherwise unchanged)
// =====================================================================
template <int MODE>
__global__ __launch_bounds__(256) void route_pass(
    const unsigned short* __restrict__ uhat,  // [CB][512][80] fp16
    const float* __restrict__ s0q,            // [8][CB][80] (MODE 1)
    const float* __restrict__ vsum_in,        // [CB][80] (MODE 2)
    float* __restrict__ vsum_out,             // [CB][80] (MODE 1)
    float* __restrict__ out,                  // final outputs (MODE 2)
    int b0, int CB) {
  __shared__ unsigned int vph2[40];
  __shared__ float red[4][2][40];
  const int bl = blockIdx.x;
  const int b  = b0 + bl;
  const int t  = threadIdx.x;

  float v0r = 0.f;
  if (t < 80) {
    if (MODE == 1) {
      float s = 0.f;
#pragma unroll
      for (int g = 0; g < 8; ++g) s += s0q[((size_t)g * CB + bl) * 80 + t];
      s *= 0.2f;
      float sq = s * s;
      sq += __shfl_xor(sq, 1);
      sq += __shfl_xor(sq, 2);
      sq += __shfl_xor(sq, 4);
      sq += __shfl_xor(sq, 8);
      const float scale = sq / (1.f + sq) / sqrtf(sq + 1e-8f);
      v0r = s * scale;
    } else {
      v0r = vsum_in[(size_t)bl * 80 + t];
    }
    const float vnext = __shfl_down(v0r, 1);
    if ((t & 1) == 0)
      vph2[t >> 1] = __builtin_bit_cast(unsigned int, __floats2half2_rn(v0r, vnext));
  }
  __syncthreads();

  const int p = t >> 1, h = t & 1;
  float acc[5][8];
#pragma unroll
  for (int o = 0; o < 5; ++o)
#pragma unroll
    for (int j = 0; j < 8; ++j) acc[o][j] = 0.f;

  const unsigned short* ub = uhat + (size_t)bl * 40960;
  for (int c4 = 0; c4 < 4; ++c4) {
    const int n = c4 * 128 + p;
    const unsigned short* row = ub + n * 80 + h * 8;
    uint4 uv[5];
#pragma unroll
    for (int o = 0; o < 5; ++o) uv[o] = *(const uint4*)(row + o * 16);
    float ap[5];
#pragma unroll
    for (int o = 0; o < 5; ++o) {
      const int vb = o * 8 + h * 4;
      float a = fdot2(u2h2(uv[o].x), u2h2(vph2[vb]), 0.f);
      a = fdot2(u2h2(uv[o].y), u2h2(vph2[vb + 1]), a);
      a = fdot2(u2h2(uv[o].z), u2h2(vph2[vb + 2]), a);
      a = fdot2(u2h2(uv[o].w), u2h2(vph2[vb + 3]), a);
      ap[o] = a + __shfl_xor(a, 1);
    }
    float m = ap[0];
#pragma unroll
    for (int o = 1; o < 5; ++o) m = fmaxf(m, ap[o]);
    float es = 0.f, e[5];
#pragma unroll
    for (int o = 0; o < 5; ++o) { e[o] = __expf(ap[o] - m); es += e[o]; }
    const float inv = 1.f / es;
#pragma unroll
    for (int o = 0; o < 5; ++o) {
      const float cc = e[o] * inv;
      h2 hx = u2h2(uv[o].x), hy = u2h2(uv[o].y), hz = u2h2(uv[o].z), hw = u2h2(uv[o].w);
      acc[o][0] += cc * (float)hx[0]; acc[o][1] += cc * (float)hx[1];
      acc[o][2] += cc * (float)hy[0]; acc[o][3] += cc * (float)hy[1];
      acc[o][4] += cc * (float)hz[0]; acc[o][5] += cc * (float)hz[1];
      acc[o][6] += cc * (float)hw[0]; acc[o][7] += cc * (float)hw[1];
    }
  }

#pragma unroll
  for (int off = 2; off <= 32; off <<= 1)
#pragma unroll
    for (int o = 0; o < 5; ++o)
#pragma unroll
      for (int j = 0; j < 8; ++j) acc[o][j] += __shfl_xor(acc[o][j], off);
  const int wid = t >> 6, lane = t & 63;
  if (lane < 2) {
#pragma unroll
    for (int o = 0; o < 5; ++o)
#pragma unroll
      for (int j = 0; j < 8; ++j) red[wid][lane][o * 8 + j] = acc[o][j];
  }
  __syncthreads();

  if (t < 80) {
    const int o = t >> 4, d = t & 15, hh = d >> 3, dl = d & 7;
    const int c = o * 8 + dl;
    float s = red[0][hh][c] + red[1][hh][c] + red[2][hh][c] + red[3][hh][c];
    float sq = s * s;
    sq += __shfl_xor(sq, 1);
    sq += __shfl_xor(sq, 2);
    sq += __shfl_xor(sq, 4);
    sq += __shfl_xor(sq, 8);
    const float scale = sq / (1.f + sq) / sqrtf(sq + 1e-8f);
    const float vn = s * scale;
    if (MODE == 1) {
      vsum_out[(size_t)bl * 80 + t] = v0r + vn;
    } else {
      out[5 * BSZ + (size_t)b * 80 + t] = vn;
      float vv = vn * vn;
      vv += __shfl_xor(vv, 1);
      vv += __shfl_xor(vv, 2);
      vv += __shfl_xor(vv, 4);
      vv += __shfl_xor(vv, 8);
      if ((t & 15) == 0) out[(size_t)b * 5 + o] = sqrtf(vv);
    }
  }
}

// =====================================================================
extern "C" void kernel_launch(void* const* d_in, const int* in_sizes, int n_in,
                              void* d_out, int out_size, void* d_ws, size_t ws_size,
                              hipStream_t stream) {
  const float* x     = (const float*)d_in[0];
  const float* W1    = (const float*)d_in[1];
  const float* b1    = (const float*)d_in[2];
  const float* convW = (const float*)d_in[3];
  const float* convB = (const float*)d_in[4];
  const float* Wr    = (const float*)d_in[5];
  float* out = (float*)d_out;

  char* base = (char*)d_ws;
  size_t off = 0;
  auto alloc = [&](size_t bytes) { size_t o = off; off = (off + bytes + 255) & ~(size_t)255; return o; };
  // persistent (live across routing phase)
  const size_t o_wrh  = alloc((size_t)NCAP * 640 * 2);       // 0.66 MB fp16
  const size_t o_u    = alloc((size_t)BSZ * 4096 * 2);       // 8.4 MB fp16
  const size_t o_s0q  = alloc((size_t)8 * BSZ * 80 * 4);     // 2.6 MB f32
  const size_t o_vsum = alloc((size_t)BSZ * 80 * 4);         // 0.33 MB f32
  // pool: phase 1-2 buffers, later reused for u_hat
  const size_t o_pool = off;
  size_t poff = o_pool;
  auto palloc = [&](size_t bytes) { size_t o = poff; poff = (poff + bytes + 255) & ~(size_t)255; return o; };
  const size_t o_ht  = palloc((size_t)BSZ * PROJ * 2);       // 18.9 MB bf16
  const size_t o_w1t = palloc((size_t)PROJ * INDIM * 2);     // 14.2 MB bf16
  const size_t o_xb  = palloc((size_t)BSZ * INDIM * 2);      // 1.6 MB bf16
  const size_t o_wt2 = palloc((size_t)256 * K2 * 2);         // 1.2 MB bf16
  const size_t o_pb1 = palloc((size_t)PROJ * 4);             // 36 KB f32
  const size_t o_cv  = palloc((size_t)BSZ * 16 * 256 * 2);   // 8.4 MB fp16

  unsigned short* ht   = (unsigned short*)(base + o_ht);
  unsigned short* w1t  = (unsigned short*)(base + o_w1t);
  unsigned short* xb   = (unsigned short*)(base + o_xb);
  unsigned short* wt2  = (unsigned short*)(base + o_wt2);
  float*          pb1  = (float*)(base + o_pb1);
  unsigned short* wrh  = (unsigned short*)(base + o_wrh);
  unsigned short* cv   = (unsigned short*)(base + o_cv);
  __half2*        u    = (__half2*)(base + o_u);
  float*          s0q  = (float*)(base + o_s0q);
  float*          vsum = (float*)(base + o_vsum);
  unsigned short* uhat = (unsigned short*)(base + o_pool);   // aliases dead phase-1/2 buffers

  convert_bf16<<<(BSZ * INDIM / 4 + 255) / 256, 256, 0, stream>>>(x, xb, BSZ * INDIM / 4);
  transpose_w1_perm<<<dim3(PROJ / 32, INDIM / 32), 256, 0, stream>>>(W1, w1t);
  perm_bias<<<PROJ / 256, 256, 0, stream>>>(b1, pb1);
  convw_prep2<<<256, 256, 0, stream>>>(convW, wt2);
  convert_f16<<<(NCAP * 640 / 4 + 255) / 256, 256, 0, stream>>>(Wr, (__half2*)wrh, NCAP * 640 / 4);

  // ht = relu(x @ W1 + b1) in [b][sp][c] layout
  mfma_gemm<1, 1><<<dim3(PROJ / 128, BSZ / 128), 256, 0, stream>>>(
      xb, w1t, pb1, (void*)ht, BSZ, PROJ, INDIM);

  // conv as implicit-im2col GEMM (no materialized im2col buffer)
  conv_gemm<<<dim3(2, 256), 256, 0, stream>>>(ht, wt2, convB, cv);

  squash_u<<<BSZ, 256, 0, stream>>>(cv, u);

  // routing: u_hat chunked over b to fit the pool
  const size_t pool_sz = ws_size > o_pool ? ws_size - o_pool : 0;
  int CB = 1024;
  while (CB > 16 && (size_t)CB * 512 * 80 * 2 > pool_sz) CB >>= 1;
  for (int b0 = 0; b0 < BSZ; b0 += CB) {
    uhat_gemm<<<dim3(CB / 16, 8), 512, 0, stream>>>(
        (const unsigned short*)u, wrh, uhat, s0q, b0, CB);
    route_pass<1><<<CB, 256, 0, stream>>>(uhat, s0q, nullptr, vsum, out, b0, CB);
    route_pass<2><<<CB, 256, 0, stream>>>(uhat, nullptr, vsum, nullptr, out, b0, CB);
  }
}

// Round 8
// 152.767 us; speedup vs baseline: 7.2150x; 1.0493x over previous
//
#include <hip/hip_runtime.h>
#include <hip/hip_fp16.h>

#define BSZ   1024
#define INDIM 768
#define PROJ  9216     // 256*6*6
#define NCAP  512
#define NCLS  5
#define K2    2304     // conv GEMM K = 9 taps * 256 ic

typedef __bf16    bf16x8 __attribute__((ext_vector_type(8)));
typedef _Float16  f16x8  __attribute__((ext_vector_type(8)));
typedef float     f32x4  __attribute__((ext_vector_type(4)));
typedef _Float16  h2     __attribute__((ext_vector_type(2)));

static __device__ __forceinline__ unsigned short f2bf(float f) {
  unsigned int x = __float_as_uint(f);
  return (unsigned short)((x + 0x7fffu + ((x >> 16) & 1u)) >> 16);
}
static __device__ __forceinline__ float bf2f(unsigned int u) {
  return __uint_as_float(u << 16);
}

#if defined(__has_builtin)
#if __has_builtin(__builtin_amdgcn_fdot2)
#define HAVE_FDOT2 1
#endif
#endif
static __device__ __forceinline__ float fdot2(h2 a, h2 b, float c) {
#ifdef HAVE_FDOT2
  return __builtin_amdgcn_fdot2(a, b, c, false);
#else
  return c + (float)a[0] * (float)b[0] + (float)a[1] * (float)b[1];
#endif
}
static __device__ __forceinline__ h2 u2h2(unsigned int u) {
  return __builtin_bit_cast(h2, u);
}
static __device__ __forceinline__ unsigned short f2h(float f) {
  return __builtin_bit_cast(unsigned short, (_Float16)f);
}

// global -> LDS direct (16B per lane)
static __device__ __forceinline__ void gload16(const void* g, void* l) {
  auto gp = reinterpret_cast<const unsigned int __attribute__((address_space(1)))*>(
      (unsigned long long)g);
  auto lp = reinterpret_cast<unsigned int __attribute__((address_space(3)))*>(
      (unsigned long long)l);
  __builtin_amdgcn_global_load_lds(gp, lp, 16, 0, 0);
}

// =====================================================================
// Unified bf16 MFMA GEMM (unchanged — passing)
// =====================================================================
template <int RELU, int OBF16>
__global__ __launch_bounds__(256) void mfma_gemm(
    const unsigned short* __restrict__ A,   // [M][K] bf16
    const unsigned short* __restrict__ Bt,  // [N][K] bf16
    const float* __restrict__ bias,         // [N]
    void* __restrict__ Cout,                // [M][N] f32 or bf16
    int M, int N, int K) {
  __shared__ __align__(16) unsigned short smem[16384];
  const int t    = threadIdx.x;
  const int bn   = blockIdx.x * 128;
  const int bm   = blockIdx.y * 128;
  const int lane = t & 63;
  const int wid  = t >> 6;
  const int wm   = (wid >> 1) * 64;
  const int wn   = (wid & 1) * 64;
  const int l15  = lane & 15;
  const int kb   = lane >> 4;

  const int r0 = t >> 2,         kc = t & 3;
  const int r1 = (t + 256) >> 2;
  const int gk0 = ((kc ^ (r0 & 3)) << 3);
  const int gk1 = ((kc ^ (r1 & 3)) << 3);

  const unsigned short* Ar0 = A  + (size_t)(bm + r0) * K + gk0;
  const unsigned short* Ar1 = A  + (size_t)(bm + r1) * K + gk1;
  const unsigned short* Br0 = Bt + (size_t)(bn + r0) * K + gk0;
  const unsigned short* Br1 = Bt + (size_t)(bn + r1) * K + gk1;

  int aoff[4], boff[4];
#pragma unroll
  for (int i = 0; i < 4; ++i) {
    const int ra = wm + i * 16 + l15;
    aoff[i] = ra * 32 + ((kb ^ (ra & 3)) << 3);
    const int rb = wn + i * 16 + l15;
    boff[i] = 4096 + rb * 32 + ((kb ^ (rb & 3)) << 3);
  }

  f32x4 acc[4][4];
#pragma unroll
  for (int i = 0; i < 4; ++i)
#pragma unroll
    for (int j = 0; j < 4; ++j)
#pragma unroll
      for (int q = 0; q < 4; ++q) acc[i][j][q] = 0.f;

  const int nk = K >> 5;
  gload16(Ar0, &smem[t * 8]);
  gload16(Ar1, &smem[(t + 256) * 8]);
  gload16(Br0, &smem[4096 + t * 8]);
  gload16(Br1, &smem[4096 + (t + 256) * 8]);
  __syncthreads();

  int buf = 0;
  for (int ks = 0; ks < nk; ++ks) {
    if (ks + 1 < nk) {
      const int k = (ks + 1) << 5;
      const int o = (buf ^ 1) * 8192;
      gload16(Ar0 + k, &smem[o + t * 8]);
      gload16(Ar1 + k, &smem[o + (t + 256) * 8]);
      gload16(Br0 + k, &smem[o + 4096 + t * 8]);
      gload16(Br1 + k, &smem[o + 4096 + (t + 256) * 8]);
    }
    const unsigned short* base = &smem[buf * 8192];
    bf16x8 af[4], bfr[4];
#pragma unroll
    for (int i = 0; i < 4; ++i) {
      af[i]  = *(const bf16x8*)(base + aoff[i]);
      bfr[i] = *(const bf16x8*)(base + boff[i]);
    }
#pragma unroll
    for (int i = 0; i < 4; ++i)
#pragma unroll
      for (int j = 0; j < 4; ++j)
        acc[i][j] = __builtin_amdgcn_mfma_f32_16x16x32_bf16(af[i], bfr[j], acc[i][j], 0, 0, 0);
    __syncthreads();
    buf ^= 1;
  }

#pragma unroll
  for (int j = 0; j < 4; ++j) {
    const int col = bn + wn + j * 16 + l15;
    const float bv = bias[col];
#pragma unroll
    for (int i = 0; i < 4; ++i) {
#pragma unroll
      for (int q = 0; q < 4; ++q) {
        const int row = bm + wm + i * 16 + kb * 4 + q;
        float v = acc[i][j][q] + bv;
        if (RELU) v = fmaxf(v, 0.f);
        if (OBF16) ((unsigned short*)Cout)[(size_t)row * N + col] = f2bf(v);
        else       ((float*)Cout)[(size_t)row * N + col] = v;
      }
    }
  }
}

// =====================================================================
// conv_gemm_sq: implicit-im2col conv GEMM, BK=64 (36 K-steps), fused
// squash epilogue writing u fp16 directly (no cv buffer, no squash_u).
// Tile 64x128, 4 waves (each 64x32), grid (2, 256).
// =====================================================================
__global__ __launch_bounds__(256) void conv_gemm_sq(
    const unsigned short* __restrict__ ht,   // [1024][36][256] bf16
    const unsigned short* __restrict__ Wt2,  // [256][2304] bf16
    const float* __restrict__ convB,         // [256]
    unsigned short* __restrict__ U) {        // [1024][32][16][8] fp16
  __shared__ __align__(16) unsigned short smem[24576];  // 2 bufs * (A 4096 + B 8192)
  const int t    = threadIdx.x;
  const int bn   = blockIdx.x * 128;
  const int bm   = blockIdx.y * 64;
  const int lane = t & 63, wid = t >> 6;
  const int l15  = lane & 15, kb = lane >> 4;

  // A staging: 512 chunks of 16B (64 rows x 8 segs); thread stages c=t, t+256
  const unsigned short* asrc[2];
#pragma unroll
  for (int cc = 0; cc < 2; ++cc) {
    const int c = t + cc * 256;
    const int row = c >> 3, seg = c & 7;
    const int gr = bm + row, b = gr >> 4, p = gr & 15;
    const int spb = (p >> 2) * 6 + (p & 3);
    asrc[cc] = ht + (size_t)b * PROJ + spb * 256 + ((seg ^ (row & 7)) << 3);
  }
  // B staging: 1024 chunks (128 rows x 8 segs); thread stages 4
  const unsigned short* bsrc[4];
#pragma unroll
  for (int cc = 0; cc < 4; ++cc) {
    const int c = t + cc * 256;
    const int row = c >> 3, seg = c & 7;
    bsrc[cc] = Wt2 + (size_t)(bn + row) * K2 + ((seg ^ (row & 7)) << 3);
  }

  // fragment LDS offsets (row stride 64 ushorts; seg = kk*4 + kb)
  int aoff[4][2], boff[2][2];
#pragma unroll
  for (int i = 0; i < 4; ++i)
#pragma unroll
    for (int kk = 0; kk < 2; ++kk) {
      const int row = i * 16 + l15, seg = kk * 4 + kb;
      aoff[i][kk] = row * 64 + ((seg ^ (row & 7)) << 3);
    }
#pragma unroll
  for (int j = 0; j < 2; ++j)
#pragma unroll
    for (int kk = 0; kk < 2; ++kk) {
      const int row = wid * 32 + j * 16 + l15, seg = kk * 4 + kb;
      boff[j][kk] = 4096 + row * 64 + ((seg ^ (row & 7)) << 3);
    }

  f32x4 acc[4][2];
#pragma unroll
  for (int i = 0; i < 4; ++i)
#pragma unroll
    for (int j = 0; j < 2; ++j)
#pragma unroll
      for (int q = 0; q < 4; ++q) acc[i][j][q] = 0.f;

  auto stage = [&](int ks, int buf) {
    const int tap  = ks >> 2;                       // 64 k per step, 256 per tap
    const int aofs = (tap + 3 * (tap / 3)) * 256 + ((ks & 3) << 6);
    const int bofs = ks << 6;
    unsigned short* sb = &smem[buf * 12288];
    gload16(asrc[0] + aofs, sb + t * 8);
    gload16(asrc[1] + aofs, sb + t * 8 + 2048);
    gload16(bsrc[0] + bofs, sb + 4096 + t * 8);
    gload16(bsrc[1] + bofs, sb + 4096 + t * 8 + 2048);
    gload16(bsrc[2] + bofs, sb + 4096 + t * 8 + 4096);
    gload16(bsrc[3] + bofs, sb + 4096 + t * 8 + 6144);
  };

  stage(0, 0);
  __syncthreads();

  int buf = 0;
  for (int ks = 0; ks < 36; ++ks) {
    if (ks + 1 < 36) stage(ks + 1, buf ^ 1);
    const unsigned short* base = &smem[buf * 12288];
    bf16x8 af[4][2], bfr[2][2];
#pragma unroll
    for (int i = 0; i < 4; ++i)
#pragma unroll
      for (int kk = 0; kk < 2; ++kk) af[i][kk] = *(const bf16x8*)(base + aoff[i][kk]);
#pragma unroll
    for (int j = 0; j < 2; ++j)
#pragma unroll
      for (int kk = 0; kk < 2; ++kk) bfr[j][kk] = *(const bf16x8*)(base + boff[j][kk]);
#pragma unroll
    for (int kk = 0; kk < 2; ++kk)
#pragma unroll
      for (int i = 0; i < 4; ++i)
#pragma unroll
        for (int j = 0; j < 2; ++j)
          acc[i][j] = __builtin_amdgcn_mfma_f32_16x16x32_bf16(af[i][kk], bfr[j][kk], acc[i][j], 0, 0, 0);
    __syncthreads();
    buf ^= 1;
  }

  // epilogue: bias + squash over 8 channels (lanes l15 grouped by 8) + u write
#pragma unroll
  for (int j = 0; j < 2; ++j) {
    const int oc  = bn + wid * 32 + j * 16 + l15;
    const int cap = oc >> 3, ii = oc & 7;
    const float bv = convB[oc];
#pragma unroll
    for (int i = 0; i < 4; ++i) {
#pragma unroll
      for (int q = 0; q < 4; ++q) {
        const int row = bm + i * 16 + kb * 4 + q;
        const int b = row >> 4, p = row & 15;
        const float val = acc[i][j][q] + bv;
        float sq = val * val;
        sq += __shfl_xor(sq, 1);
        sq += __shfl_xor(sq, 2);
        sq += __shfl_xor(sq, 4);
        const float scale = sq / (1.f + sq) / sqrtf(sq + 1e-8f);
        U[(size_t)b * 4096 + cap * 128 + p * 8 + ii] = f2h(val * scale);
      }
    }
  }
}

// =====================================================================
// Transforms
// =====================================================================
__global__ __launch_bounds__(256) void convert_bf16(const float* __restrict__ in,
                                                    unsigned short* __restrict__ out,
                                                    int n4) {
  const int i = blockIdx.x * 256 + threadIdx.x;
  if (i >= n4) return;
  float4 v = ((const float4*)in)[i];
  ushort4 o;
  o.x = f2bf(v.x); o.y = f2bf(v.y); o.z = f2bf(v.z); o.w = f2bf(v.w);
  ((ushort4*)out)[i] = o;
}

__global__ __launch_bounds__(256) void convert_f16(const float* __restrict__ in,
                                                   __half2* __restrict__ out, int n4) {
  const int i = blockIdx.x * 256 + threadIdx.x;
  if (i >= n4) return;
  float4 v = ((const float4*)in)[i];
  out[i * 2]     = __floats2half2_rn(v.x, v.y);
  out[i * 2 + 1] = __floats2half2_rn(v.z, v.w);
}

__global__ __launch_bounds__(256) void transpose_w1_perm(const float* __restrict__ W,
                                                         unsigned short* __restrict__ Wt) {
  __shared__ float tile[32][33];
  const int n0 = blockIdx.x * 32, k0 = blockIdx.y * 32;
  const int r = threadIdx.x >> 3, c = (threadIdx.x & 7) * 4;
  float4 v = *(const float4*)(W + (size_t)(k0 + r) * PROJ + n0 + c);
  tile[r][c] = v.x; tile[r][c + 1] = v.y; tile[r][c + 2] = v.z; tile[r][c + 3] = v.w;
  __syncthreads();
  ushort4 o;
  o.x = f2bf(tile[c + 0][r]); o.y = f2bf(tile[c + 1][r]);
  o.z = f2bf(tile[c + 2][r]); o.w = f2bf(tile[c + 3][r]);
  const int nn = n0 + r;
  const int prow = (nn % 36) * 256 + nn / 36;
  *(ushort4*)(Wt + (size_t)prow * INDIM + k0 + c) = o;
}

__global__ __launch_bounds__(256) void perm_bias(const float* __restrict__ b1,
                                                 float* __restrict__ pb1) {
  const int n = blockIdx.x * 256 + threadIdx.x;
  if (n >= PROJ) return;
  pb1[(n % 36) * 256 + n / 36] = b1[n];
}

__global__ __launch_bounds__(256) void convw_prep2(const float* __restrict__ W,
                                                   unsigned short* __restrict__ Wt2) {
  const int id = blockIdx.x * 256 + threadIdx.x;
  const int oc = id >> 8, ic = id & 255;
  const float* s = W + (size_t)id * 9;
#pragma unroll
  for (int tap = 0; tap < 9; ++tap)
    Wt2[(size_t)oc * K2 + tap * 256 + ic] = f2bf(s[tap]);
}

// =====================================================================
// uhat_gemm v2 (unchanged — passing)
// =====================================================================
__global__ __launch_bounds__(512) void uhat_gemm(
    const unsigned short* __restrict__ U,    // [1024][512][8] fp16
    const unsigned short* __restrict__ Wrh,  // [512][80][8] fp16
    unsigned short* __restrict__ uhat,       // [CB][512][80] fp16
    float* __restrict__ s0q,                 // [8][CB][80]
    int b0, int CB) {
  __shared__ float sred[8][16][80];  // 40 KB
  const int mt = blockIdx.x, q = blockIdx.y;   // q 0..7
  const int t = threadIdx.x, wid = t >> 6, lane = t & 63;
  const int l15 = lane & 15, kb = lane >> 4;
  const int bm = mt * 16;
  const int gb = b0 + bm;

  f32x4 sacc[5];
#pragma unroll
  for (int j = 0; j < 5; ++j)
#pragma unroll
    for (int r = 0; r < 4; ++r) sacc[j][r] = 0.f;

  const uint4 zz = make_uint4(0, 0, 0, 0);
#pragma unroll
  for (int i = 0; i < 8; ++i) {
    const int n = q * 64 + wid * 8 + i;
    uint4 av = zz;
    if (kb == 0) av = *(const uint4*)(U + (size_t)(gb + l15) * 4096 + n * 8);
    const f16x8 uf = __builtin_bit_cast(f16x8, av);
#pragma unroll
    for (int jn = 0; jn < 5; ++jn) {
      uint4 wv = zz;
      if (kb == 0) wv = *(const uint4*)(Wrh + (size_t)n * 640 + (jn * 16 + l15) * 8);
      f32x4 z;
      z[0] = 0.f; z[1] = 0.f; z[2] = 0.f; z[3] = 0.f;
      f32x4 c = __builtin_amdgcn_mfma_f32_16x16x32_f16(
          __builtin_bit_cast(f16x8, wv), uf, z, 0, 0, 0);
      ushort4 st;
      st.x = f2h(c[0]); st.y = f2h(c[1]); st.z = f2h(c[2]); st.w = f2h(c[3]);
      *(ushort4*)(uhat + ((size_t)(bm + l15) * 512 + n) * 80 + jn * 16 + kb * 4) = st;
#pragma unroll
      for (int qq = 0; qq < 4; ++qq) sacc[jn][qq] += c[qq];
    }
  }

#pragma unroll
  for (int jn = 0; jn < 5; ++jn)
#pragma unroll
    for (int qq = 0; qq < 4; ++qq)
      sred[wid][l15][jn * 16 + kb * 4 + qq] = sacc[jn][qq];
  __syncthreads();
#pragma unroll
  for (int k = 0; k < 3; ++k) {
    const int id = t + k * 512;
    if (id < 1280) {
      const int bb = id / 80, od = id % 80;
      float val = 0.f;
#pragma unroll
      for (int w = 0; w < 8; ++w) val += sred[w][bb][od];
      s0q[((size_t)q * CB + bm + bb) * 80 + od] = val;
    }
  }
}

// =====================================================================
// route_pass<MODE> (unchanged — passing)
// =====================================================================
template <int MODE>
__global__ __launch_bounds__(256) void route_pass(
    const unsigned short* __restrict__ uhat,  // [CB][512][80] fp16
    const float* __restrict__ s0q,            // [8][CB][80] (MODE 1)
    const float* __restrict__ vsum_in,        // [CB][80] (MODE 2)
    float* __restrict__ vsum_out,             // [CB][80] (MODE 1)
    float* __restrict__ out,                  // final outputs (MODE 2)
    int b0, int CB) {
  __shared__ unsigned int vph2[40];
  __shared__ float red[4][2][40];
  const int bl = blockIdx.x;
  const int b  = b0 + bl;
  const int t  = threadIdx.x;

  float v0r = 0.f;
  if (t < 80) {
    if (MODE == 1) {
      float s = 0.f;
#pragma unroll
      for (int g = 0; g < 8; ++g) s += s0q[((size_t)g * CB + bl) * 80 + t];
      s *= 0.2f;
      float sq = s * s;
      sq += __shfl_xor(sq, 1);
      sq += __shfl_xor(sq, 2);
      sq += __shfl_xor(sq, 4);
      sq += __shfl_xor(sq, 8);
      const float scale = sq / (1.f + sq) / sqrtf(sq + 1e-8f);
      v0r = s * scale;
    } else {
      v0r = vsum_in[(size_t)bl * 80 + t];
    }
    const float vnext = __shfl_down(v0r, 1);
    if ((t & 1) == 0)
      vph2[t >> 1] = __builtin_bit_cast(unsigned int, __floats2half2_rn(v0r, vnext));
  }
  __syncthreads();

  const int p = t >> 1, h = t & 1;
  float acc[5][8];
#pragma unroll
  for (int o = 0; o < 5; ++o)
#pragma unroll
    for (int j = 0; j < 8; ++j) acc[o][j] = 0.f;

  const unsigned short* ub = uhat + (size_t)bl * 40960;
  for (int c4 = 0; c4 < 4; ++c4) {
    const int n = c4 * 128 + p;
    const unsigned short* row = ub + n * 80 + h * 8;
    uint4 uv[5];
#pragma unroll
    for (int o = 0; o < 5; ++o) uv[o] = *(const uint4*)(row + o * 16);
    float ap[5];
#pragma unroll
    for (int o = 0; o < 5; ++o) {
      const int vb = o * 8 + h * 4;
      float a = fdot2(u2h2(uv[o].x), u2h2(vph2[vb]), 0.f);
      a = fdot2(u2h2(uv[o].y), u2h2(vph2[vb + 1]), a);
      a = fdot2(u2h2(uv[o].z), u2h2(vph2[vb + 2]), a);
      a = fdot2(u2h2(uv[o].w), u2h2(vph2[vb + 3]), a);
      ap[o] = a + __shfl_xor(a, 1);
    }
    float m = ap[0];
#pragma unroll
    for (int o = 1; o < 5; ++o) m = fmaxf(m, ap[o]);
    float es = 0.f, e[5];
#pragma unroll
    for (int o = 0; o < 5; ++o) { e[o] = __expf(ap[o] - m); es += e[o]; }
    const float inv = 1.f / es;
#pragma unroll
    for (int o = 0; o < 5; ++o) {
      const float cc = e[o] * inv;
      h2 hx = u2h2(uv[o].x), hy = u2h2(uv[o].y), hz = u2h2(uv[o].z), hw = u2h2(uv[o].w);
      acc[o][0] += cc * (float)hx[0]; acc[o][1] += cc * (float)hx[1];
      acc[o][2] += cc * (float)hy[0]; acc[o][3] += cc * (float)hy[1];
      acc[o][4] += cc * (float)hz[0]; acc[o][5] += cc * (float)hz[1];
      acc[o][6] += cc * (float)hw[0]; acc[o][7] += cc * (float)hw[1];
    }
  }

#pragma unroll
  for (int off = 2; off <= 32; off <<= 1)
#pragma unroll
    for (int o = 0; o < 5; ++o)
#pragma unroll
      for (int j = 0; j < 8; ++j) acc[o][j] += __shfl_xor(acc[o][j], off);
  const int wid = t >> 6, lane = t & 63;
  if (lane < 2) {
#pragma unroll
    for (int o = 0; o < 5; ++o)
#pragma unroll
      for (int j = 0; j < 8; ++j) red[wid][lane][o * 8 + j] = acc[o][j];
  }
  __syncthreads();

  if (t < 80) {
    const int o = t >> 4, d = t & 15, hh = d >> 3, dl = d & 7;
    const int c = o * 8 + dl;
    float s = red[0][hh][c] + red[1][hh][c] + red[2][hh][c] + red[3][hh][c];
    float sq = s * s;
    sq += __shfl_xor(sq, 1);
    sq += __shfl_xor(sq, 2);
    sq += __shfl_xor(sq, 4);
    sq += __shfl_xor(sq, 8);
    const float scale = sq / (1.f + sq) / sqrtf(sq + 1e-8f);
    const float vn = s * scale;
    if (MODE == 1) {
      vsum_out[(size_t)bl * 80 + t] = v0r + vn;
    } else {
      out[5 * BSZ + (size_t)b * 80 + t] = vn;
      float vv = vn * vn;
      vv += __shfl_xor(vv, 1);
      vv += __shfl_xor(vv, 2);
      vv += __shfl_xor(vv, 4);
      vv += __shfl_xor(vv, 8);
      if ((t & 15) == 0) out[(size_t)b * 5 + o] = sqrtf(vv);
    }
  }
}

// =====================================================================
extern "C" void kernel_launch(void* const* d_in, const int* in_sizes, int n_in,
                              void* d_out, int out_size, void* d_ws, size_t ws_size,
                              hipStream_t stream) {
  const float* x     = (const float*)d_in[0];
  const float* W1    = (const float*)d_in[1];
  const float* b1    = (const float*)d_in[2];
  const float* convW = (const float*)d_in[3];
  const float* convB = (const float*)d_in[4];
  const float* Wr    = (const float*)d_in[5];
  float* out = (float*)d_out;

  char* base = (char*)d_ws;
  size_t off = 0;
  auto alloc = [&](size_t bytes) { size_t o = off; off = (off + bytes + 255) & ~(size_t)255; return o; };
  // persistent (live across routing phase)
  const size_t o_wrh  = alloc((size_t)NCAP * 640 * 2);       // 0.66 MB fp16
  const size_t o_u    = alloc((size_t)BSZ * 4096 * 2);       // 8.4 MB fp16
  const size_t o_s0q  = alloc((size_t)8 * BSZ * 80 * 4);     // 2.6 MB f32
  const size_t o_vsum = alloc((size_t)BSZ * 80 * 4);         // 0.33 MB f32
  // pool: phase 1-2 buffers, later reused for u_hat
  const size_t o_pool = off;
  size_t poff = o_pool;
  auto palloc = [&](size_t bytes) { size_t o = poff; poff = (poff + bytes + 255) & ~(size_t)255; return o; };
  const size_t o_ht  = palloc((size_t)BSZ * PROJ * 2);       // 18.9 MB bf16
  const size_t o_w1t = palloc((size_t)PROJ * INDIM * 2);     // 14.2 MB bf16
  const size_t o_xb  = palloc((size_t)BSZ * INDIM * 2);      // 1.6 MB bf16
  const size_t o_wt2 = palloc((size_t)256 * K2 * 2);         // 1.2 MB bf16
  const size_t o_pb1 = palloc((size_t)PROJ * 4);             // 36 KB f32

  unsigned short* ht   = (unsigned short*)(base + o_ht);
  unsigned short* w1t  = (unsigned short*)(base + o_w1t);
  unsigned short* xb   = (unsigned short*)(base + o_xb);
  unsigned short* wt2  = (unsigned short*)(base + o_wt2);
  float*          pb1  = (float*)(base + o_pb1);
  unsigned short* wrh  = (unsigned short*)(base + o_wrh);
  unsigned short* u    = (unsigned short*)(base + o_u);
  float*          s0q  = (float*)(base + o_s0q);
  float*          vsum = (float*)(base + o_vsum);
  unsigned short* uhat = (unsigned short*)(base + o_pool);   // aliases dead phase-1/2 buffers

  convert_bf16<<<(BSZ * INDIM / 4 + 255) / 256, 256, 0, stream>>>(x, xb, BSZ * INDIM / 4);
  transpose_w1_perm<<<dim3(PROJ / 32, INDIM / 32), 256, 0, stream>>>(W1, w1t);
  perm_bias<<<PROJ / 256, 256, 0, stream>>>(b1, pb1);
  convw_prep2<<<256, 256, 0, stream>>>(convW, wt2);
  convert_f16<<<(NCAP * 640 / 4 + 255) / 256, 256, 0, stream>>>(Wr, (__half2*)wrh, NCAP * 640 / 4);

  // ht = relu(x @ W1 + b1) in [b][sp][c] layout
  mfma_gemm<1, 1><<<dim3(PROJ / 128, BSZ / 128), 256, 0, stream>>>(
      xb, w1t, pb1, (void*)ht, BSZ, PROJ, INDIM);

  // conv + squash fused (implicit im2col, BK=64, u written directly)
  conv_gemm_sq<<<dim3(2, 256), 256, 0, stream>>>(ht, wt2, convB, u);

  // routing: u_hat chunked over b to fit the pool
  const size_t pool_sz = ws_size > o_pool ? ws_size - o_pool : 0;
  int CB = 1024;
  while (CB > 16 && (size_t)CB * 512 * 80 * 2 > pool_sz) CB >>= 1;
  for (int b0 = 0; b0 < BSZ; b0 += CB) {
    uhat_gemm<<<dim3(CB / 16, 8), 512, 0, stream>>>(
        u, wrh, uhat, s0q, b0, CB);
    route_pass<1><<<CB, 256, 0, stream>>>(uhat, s0q, nullptr, vsum, out, b0, CB);
    route_pass<2><<<CB, 256, 0, stream>>>(uhat, nullptr, vsum, nullptr, out, b0, CB);
  }
}